// Round 4
// baseline (639.729 us; speedup 1.0000x reference)
//
#include <hip/hip_runtime.h>
#include <math.h>

// L=32768 lines, M=8 neighbors, B=8192 blocks, LIN=BIN=768, H=512, NH=8, DH=64

typedef unsigned short u16;
typedef unsigned int u32;
using bf16x8 = __attribute__((ext_vector_type(8))) __bf16;
using u16x8  = __attribute__((ext_vector_type(8))) u16;
using f32x4  = __attribute__((ext_vector_type(4))) float;

__device__ __forceinline__ u16 f2bf(float f) {
    u32 u = __builtin_bit_cast(u32, f);
    u32 r = u + 0x7fffu + ((u >> 16) & 1u);
    return (u16)(r >> 16);
}
__device__ __forceinline__ float bf2f(u16 h) {
    return __builtin_bit_cast(float, (u32)h << 16);
}
__device__ __forceinline__ float gelu_exact(float x) {
    return 0.5f * x * (1.0f + erff(x * 0.70710678118654752440f));
}

// ---------------- fused multi-array conversion (weights) ----------------
struct CvtJobs {
    const float* s[6];
    u16* d[6];
    int cum[7];   // cumulative quad counts
};
__global__ __launch_bounds__(256) void cvt_multi(CvtJobs j)
{
    const int g = blockIdx.x * 256 + threadIdx.x;   // quad index
    if (g >= j.cum[6]) return;
    int seg = 0;
    #pragma unroll
    for (int k = 1; k < 6; ++k) seg += (g >= j.cum[k]);
    const int q = g - j.cum[seg];
    const float4 v = *reinterpret_cast<const float4*>(j.s[seg] + q * 4);
    ushort4 o = make_ushort4(f2bf(v.x), f2bf(v.y), f2bf(v.z), f2bf(v.w));
    *reinterpret_cast<ushort4*>(j.d[seg] + q * 4) = o;
}

// ---------------- tall-tile GEMM with fused epilogue ----------------
// C[M,N] = A[M,K] @ W[N,K]^T (+bias), tile = 64 rows x 512 cols, 512 threads
// (8 waves; wave w owns cols w*64..w*64+63 -> 4x4 16x16 fragments, 16 MFMA/Kstep).
// A read exactly once; optional in-flight fp32->bf16 convert (reg-staged);
// W staged via global_load_lds (bf16, pre-converted).
// EPI: 0 = bias only, write bf16
//      1 = bias + LN(g,b), write bf16            (needs gridDim.y==1)
//      2 = bias + LN + GELU, write bf16
//      3 = bias + LN + GELU + resid + head dot + sigmoid, write fp32 [M]
template<bool A_FP32, bool HAS_A2, int EPI>
__global__ __launch_bounds__(512) void gemm_tall(
    const void* __restrict__ A1v, const void* __restrict__ A2v, int K1, int K,
    const u16* __restrict__ W, const float* __restrict__ bias,
    const float* __restrict__ g, const float* __restrict__ b,
    const u16* __restrict__ resid, const float* __restrict__ hw,
    const float* __restrict__ hb, void* __restrict__ Cv, int Ntot)
{
    __shared__ __bf16 Ws_s[512 * 32];
    __shared__ __bf16 As_s[64 * 32];
    __shared__ float ssum[64][8];
    __shared__ float ssq[64][8];

    const int tid = threadIdx.x;
    const int w = tid >> 6, lane = tid & 63;
    const int fr = lane & 15, fg = lane >> 4;
    const int wc = w * 64;
    const int row0 = blockIdx.x * 64;
    const int nbase = blockIdx.y * 512;

    // A staging map: thread -> 4 bf16 elems (8B) of the 64x32 tile
    const int ar = tid >> 3;
    const int ac = (tid & 7) * 4;
    // W staging map: per wave 4 chunks of 1KB; per-lane global src offsets
    int wrow[4], wcol[4];
    #pragma unroll
    for (int c = 0; c < 4; ++c) {
        const int off = (w * 4 + c) * 1024 + lane * 16;   // byte off in [512][32] bf16
        wrow[c] = off >> 6;
        wcol[c] = (off & 63) >> 1;
    }

    f32x4 acc[4][4] = {};

    for (int k0 = 0; k0 < K; k0 += 32) {
        // stage A (reg -> LDS, optional convert)
        if (A_FP32) {
            const float* Af = (const float*)A1v;
            const float4 av = *reinterpret_cast<const float4*>(
                Af + (size_t)(row0 + ar) * K + k0 + ac);
            *reinterpret_cast<ushort4*>((u16*)As_s + ar * 32 + ac) =
                make_ushort4(f2bf(av.x), f2bf(av.y), f2bf(av.z), f2bf(av.w));
        } else {
            const u16* Ab;
            int kk;
            if (HAS_A2 && k0 >= K1) { Ab = (const u16*)A2v; kk = k0 - K1; }
            else                    { Ab = (const u16*)A1v; kk = k0; }
            const int ld = HAS_A2 ? ((k0 >= K1) ? (K - K1) : K1) : K;
            const ushort4 av = *reinterpret_cast<const ushort4*>(
                Ab + (size_t)(row0 + ar) * ld + kk + ac);
            *reinterpret_cast<ushort4*>((u16*)As_s + ar * 32 + ac) = av;
        }
        // stage W (global_load_lds, 16B/lane, wave-uniform LDS base)
        #pragma unroll
        for (int c = 0; c < 4; ++c) {
            const u16* src = W + (size_t)(nbase + wrow[c]) * K + k0 + wcol[c];
            __builtin_amdgcn_global_load_lds(
                (const __attribute__((address_space(1))) u32*)src,
                (__attribute__((address_space(3))) u32*)(Ws_s + (w * 4 + c) * 512),
                16, 0, 0);
        }
        __syncthreads();

        bf16x8 af[4], bfr[4];
        #pragma unroll
        for (int m = 0; m < 4; ++m) {
            af[m]  = *(const bf16x8*)(As_s + (m * 16 + fr) * 32 + fg * 8);
            bfr[m] = *(const bf16x8*)(Ws_s + (wc + m * 16 + fr) * 32 + fg * 8);
        }
        #pragma unroll
        for (int m = 0; m < 4; ++m)
            #pragma unroll
            for (int n = 0; n < 4; ++n)
                acc[m][n] = __builtin_amdgcn_mfma_f32_16x16x32_bf16(
                    af[m], bfr[n], acc[m][n], 0, 0, 0);
        __syncthreads();
    }

    // ---- epilogue ----
    // add bias (before LN stats)
    if (bias) {
        #pragma unroll
        for (int n = 0; n < 4; ++n) {
            const float bv = bias[nbase + wc + n * 16 + fr];
            #pragma unroll
            for (int m = 0; m < 4; ++m)
                #pragma unroll
                for (int r = 0; r < 4; ++r)
                    acc[m][n][r] += bv;
        }
    }

    if (EPI == 0) {
        u16* C = (u16*)Cv;
        #pragma unroll
        for (int m = 0; m < 4; ++m)
            #pragma unroll
            for (int n = 0; n < 4; ++n) {
                const int col = nbase + wc + n * 16 + fr;
                #pragma unroll
                for (int r = 0; r < 4; ++r) {
                    const int row = row0 + m * 16 + fg * 4 + r;
                    C[(size_t)row * Ntot + col] = f2bf(acc[m][n][r]);
                }
            }
        return;
    }

    // LN row stats: per-thread partials over its 4 cols, shfl over fr, LDS over waves
    float ps[4][4], pq[4][4];
    #pragma unroll
    for (int m = 0; m < 4; ++m)
        #pragma unroll
        for (int r = 0; r < 4; ++r) {
            float s = 0.0f, q2 = 0.0f;
            #pragma unroll
            for (int n = 0; n < 4; ++n) {
                const float v = acc[m][n][r];
                s += v; q2 += v * v;
            }
            ps[m][r] = s; pq[m][r] = q2;
        }
    #pragma unroll
    for (int off = 1; off < 16; off <<= 1)
        #pragma unroll
        for (int m = 0; m < 4; ++m)
            #pragma unroll
            for (int r = 0; r < 4; ++r) {
                ps[m][r] += __shfl_xor(ps[m][r], off);
                pq[m][r] += __shfl_xor(pq[m][r], off);
            }
    if (fr == 0) {
        #pragma unroll
        for (int m = 0; m < 4; ++m)
            #pragma unroll
            for (int r = 0; r < 4; ++r) {
                const int row = m * 16 + fg * 4 + r;
                ssum[row][w] = ps[m][r];
                ssq[row][w]  = pq[m][r];
            }
    }
    __syncthreads();

    float dotp[4][4];   // head partials (EPI==3)
    u16* C = (u16*)Cv;
    #pragma unroll
    for (int m = 0; m < 4; ++m) {
        #pragma unroll
        for (int r = 0; r < 4; ++r) {
            const int row = m * 16 + fg * 4 + r;
            float s = 0.0f, q2 = 0.0f;
            #pragma unroll
            for (int ww = 0; ww < 8; ++ww) { s += ssum[row][ww]; q2 += ssq[row][ww]; }
            const float mu = s * (1.0f / 512.0f);
            const float var = q2 * (1.0f / 512.0f) - mu * mu;
            const float rs = rsqrtf(var + 1e-5f);
            float dp = 0.0f;
            #pragma unroll
            for (int n = 0; n < 4; ++n) {
                const int col = wc + n * 16 + fr;     // Ntot==512 here
                float y = (acc[m][n][r] - mu) * rs * g[col] + b[col];
                if (EPI >= 2) y = gelu_exact(y);
                if (EPI == 3) {
                    y += bf2f(resid[(size_t)(row0 + row) * 512 + col]);
                    dp = fmaf(y, hw[col], dp);
                } else {
                    C[(size_t)(row0 + row) * 512 + col] = f2bf(y);
                }
            }
            dotp[m][r] = dp;
        }
    }

    if (EPI == 3) {
        #pragma unroll
        for (int off = 1; off < 16; off <<= 1)
            #pragma unroll
            for (int m = 0; m < 4; ++m)
                #pragma unroll
                for (int r = 0; r < 4; ++r)
                    dotp[m][r] += __shfl_xor(dotp[m][r], off);
        __syncthreads();   // done reading ssum for stats
        if (fr == 0) {
            #pragma unroll
            for (int m = 0; m < 4; ++m)
                #pragma unroll
                for (int r = 0; r < 4; ++r)
                    ssum[m * 16 + fg * 4 + r][w] = dotp[m][r];
        }
        __syncthreads();
        if (w == 0 && fr == 0) {
            float* out = (float*)Cv;
            #pragma unroll
            for (int m = 0; m < 4; ++m)
                #pragma unroll
                for (int r = 0; r < 4; ++r) {
                    const int row = m * 16 + fg * 4 + r;
                    float d = hb[0];
                    #pragma unroll
                    for (int ww = 0; ww < 8; ++ww) d += ssum[row][ww];
                    out[row0 + row] = 1.0f / (1.0f + expf(-d));
                }
        }
    }
}

// ---------------- Attention: wave per (line, head); lane = dgroup*8 + m -----
__global__ __launch_bounds__(512) void attn_kernel(
    const u16* __restrict__ qh, const u16* __restrict__ kvb,
    const int* __restrict__ kidx, const int* __restrict__ ncnt,
    u16* __restrict__ ctx)
{
    const int l = blockIdx.x;
    const int head = threadIdx.x >> 6;
    const int lane = threadIdx.x & 63;
    const int mi = lane & 7, dg = lane >> 3;
    const int cnt = ncnt[l];
    const int idx = kidx[l * 8 + mi];

    const u16x8 qv = *(const u16x8*)(qh + (size_t)l * 512 + head * 64 + dg * 8);
    const u16x8 kv = *(const u16x8*)(kvb + (size_t)idx * 1024 + head * 64 + dg * 8);
    float p = 0.0f;
    #pragma unroll
    for (int jj = 0; jj < 8; ++jj) p = fmaf(bf2f(qv[jj]), bf2f(kv[jj]), p);
    p += __shfl_xor(p, 8); p += __shfl_xor(p, 16); p += __shfl_xor(p, 32);

    float s = (mi < cnt) ? p * 0.125f : -3.402823466e38f;
    float mx = s;
    mx = fmaxf(mx, __shfl_xor(mx, 1));
    mx = fmaxf(mx, __shfl_xor(mx, 2));
    mx = fmaxf(mx, __shfl_xor(mx, 4));
    const float e = __expf(s - mx);
    float den = e;
    den += __shfl_xor(den, 1); den += __shfl_xor(den, 2); den += __shfl_xor(den, 4);
    const float wgt = e / den;

    const u16x8 vv = *(const u16x8*)(kvb + (size_t)idx * 1024 + 512 + head * 64 + dg * 8);
    float c[8];
    #pragma unroll
    for (int jj = 0; jj < 8; ++jj) c[jj] = wgt * bf2f(vv[jj]);

    const bool b0 = (mi & 1), b1 = (mi & 2), b2 = (mi & 4);
    #pragma unroll
    for (int jj = 0; jj < 4; ++jj) {
        const float snd = b0 ? c[jj] : c[jj + 4];
        const float rec = __shfl_xor(snd, 1);
        c[jj] = (b0 ? c[jj + 4] : c[jj]) + rec;
    }
    #pragma unroll
    for (int jj = 0; jj < 2; ++jj) {
        const float snd = b1 ? c[jj] : c[jj + 2];
        const float rec = __shfl_xor(snd, 2);
        c[jj] = (b1 ? c[jj + 2] : c[jj]) + rec;
    }
    {
        const float snd = b2 ? c[0] : c[1];
        const float rec = __shfl_xor(snd, 4);
        c[0] = (b2 ? c[1] : c[0]) + rec;
    }
    const int doff = (b0 ? 4 : 0) + (b1 ? 2 : 0) + (b2 ? 1 : 0);
    ctx[(size_t)l * 512 + head * 64 + dg * 8 + doff] = f2bf(c[0]);
}

extern "C" void kernel_launch(void* const* d_in, const int* in_sizes, int n_in,
                              void* d_out, int out_size, void* d_ws, size_t ws_size,
                              hipStream_t stream)
{
    const float* lines  = (const float*)d_in[0];   // [32768,768]
    const float* blocks = (const float*)d_in[1];   // [8192,768]
    const float* Wq     = (const float*)d_in[2];   // [512,768]
    const float* Wkv    = (const float*)d_in[3];   // [512,768]
    const float* qn_g   = (const float*)d_in[4];
    const float* qn_b   = (const float*)d_in[5];
    const float* kvn_g  = (const float*)d_in[6];
    const float* kvn_b  = (const float*)d_in[7];
    const float* in_w   = (const float*)d_in[8];   // [1536,512]
    const float* in_b   = (const float*)d_in[9];   // [1536]
    const float* out_w  = (const float*)d_in[10];  // [512,512]
    const float* out_b  = (const float*)d_in[11];
    const float* p1_w   = (const float*)d_in[12];  // [512,1024]
    const float* p1_b   = (const float*)d_in[13];
    const float* ln1_g  = (const float*)d_in[14];
    const float* ln1_b  = (const float*)d_in[15];
    const float* p2_w   = (const float*)d_in[16];  // [512,512]
    const float* p2_b   = (const float*)d_in[17];
    const float* ln2_g  = (const float*)d_in[18];
    const float* ln2_b  = (const float*)d_in[19];
    const float* head_w = (const float*)d_in[20];  // [1,512]
    const float* head_b = (const float*)d_in[21];  // [1]
    const int*   kidx   = (const int*)d_in[22];    // [32768,8]
    const int*   ncnt   = (const int*)d_in[23];    // [32768]
    float* out = (float*)d_out;                    // [32768]

    char* wsb = (char*)d_ws;
    u16* qb   = (u16*)(wsb);                    // [32768,512] bf16
    u16* qhb  = (u16*)(wsb + (32ull << 20));    // [32768,512] qh -> attn_out
    u16* ctxb = (u16*)(wsb + (64ull << 20));    // [32768,512] ctx -> h1
    u16* kvbb = (u16*)(wsb + (96ull << 20));    // [8192,1024] k|v
    u16* bkvb = (u16*)(wsb + (112ull << 20));   // [8192,512]
    u16* Wqb  = (u16*)(wsb + (120ull << 20));
    u16* Wkvb = Wqb + 512 * 768;
    u16* inwb = Wkvb + 512 * 768;
    u16* outwb = inwb + 1536 * 512;
    u16* p1wb = outwb + 512 * 512;
    u16* p2wb = p1wb + 512 * 1024;

    // weights: one fused conversion launch
    {
        CvtJobs j;
        const float* ss[6] = { Wq, Wkv, in_w, out_w, p1_w, p2_w };
        u16* dd[6] = { Wqb, Wkvb, inwb, outwb, p1wb, p2wb };
        const int nn[6] = { 512 * 768, 512 * 768, 1536 * 512, 512 * 512, 512 * 1024, 512 * 512 };
        int c = 0;
        for (int k = 0; k < 6; ++k) { j.s[k] = ss[k]; j.d[k] = dd[k]; j.cum[k] = c; c += nn[k] / 4; }
        j.cum[6] = c;
        cvt_multi<<<(c + 255) / 256, 256, 0, stream>>>(j);
    }

    // 1+2. bkvb = LN(blocks @ Wkv^T)                      [8192,512] bf16
    gemm_tall<true, false, 1><<<dim3(128, 1), 512, 0, stream>>>(
        blocks, nullptr, 768, 768, Wkvb, nullptr, kvn_g, kvn_b,
        nullptr, nullptr, nullptr, bkvb, 512);
    // 3. kvbb = bkvb @ [wk;wv]^T + [bk;bv]                [8192,1024] bf16
    gemm_tall<false, false, 0><<<dim3(128, 2), 512, 0, stream>>>(
        bkvb, nullptr, 512, 512, inwb + 512 * 512, in_b + 512, nullptr, nullptr,
        nullptr, nullptr, nullptr, kvbb, 1024);
    // 4+5. qb = LN(lines @ Wq^T)                          [32768,512] bf16
    gemm_tall<true, false, 1><<<dim3(512, 1), 512, 0, stream>>>(
        lines, nullptr, 768, 768, Wqb, nullptr, qn_g, qn_b,
        nullptr, nullptr, nullptr, qb, 512);
    // 6. qhb = qb @ wq_i^T + bq_i                         [32768,512] bf16
    gemm_tall<false, false, 0><<<dim3(512, 1), 512, 0, stream>>>(
        qb, nullptr, 512, 512, inwb, in_b, nullptr, nullptr,
        nullptr, nullptr, nullptr, qhb, 512);
    // 7. ctxb (attention)
    attn_kernel<<<32768, 512, 0, stream>>>(qhb, kvbb, kidx, ncnt, ctxb);
    // 8. attn_out = ctxb @ out_w^T + out_b   (into qhb; qh dead)
    gemm_tall<false, false, 0><<<dim3(512, 1), 512, 0, stream>>>(
        ctxb, nullptr, 512, 512, outwb, out_b, nullptr, nullptr,
        nullptr, nullptr, nullptr, qhb, 512);
    // 9+10. h1 = gelu(LN([qb|attn_out] @ p1_w^T + p1_b))  (into ctxb; ctx dead)
    gemm_tall<false, true, 2><<<dim3(512, 1), 512, 0, stream>>>(
        qb, qhb, 512, 1024, p1wb, p1_b, ln1_g, ln1_b,
        nullptr, nullptr, nullptr, ctxb, 512);
    // 11+12. out = sigmoid((h1 + gelu(LN(h1 @ p2_w^T + p2_b))) . head_w + head_b)
    gemm_tall<false, false, 3><<<dim3(512, 1), 512, 0, stream>>>(
        ctxb, nullptr, 512, 512, p2wb, p2_b, ln2_g, ln2_b,
        ctxb, head_w, head_b, out, 512);
}

// Round 5
// 524.687 us; speedup vs baseline: 1.2193x; 1.2193x over previous
//
#include <hip/hip_runtime.h>
#include <math.h>

// L=32768 lines, M=8 neighbors, B=8192 blocks, LIN=BIN=768, H=512, NH=8, DH=64

typedef unsigned short u16;
typedef unsigned int u32;
using bf16x8 = __attribute__((ext_vector_type(8))) __bf16;
using u16x8  = __attribute__((ext_vector_type(8))) u16;
using f32x4  = __attribute__((ext_vector_type(4))) float;

__device__ __forceinline__ u16 f2bf(float f) {
    u32 u = __builtin_bit_cast(u32, f);
    u32 r = u + 0x7fffu + ((u >> 16) & 1u);
    return (u16)(r >> 16);
}
__device__ __forceinline__ float bf2f(u16 h) {
    return __builtin_bit_cast(float, (u32)h << 16);
}
__device__ __forceinline__ float gelu_exact(float x) {
    return 0.5f * x * (1.0f + erff(x * 0.70710678118654752440f));
}

// Block-wide reduction of two values across 256 threads (4 waves).
__device__ __forceinline__ void breduce2(float& s0, float& s1, float* sm) {
    #pragma unroll
    for (int off = 32; off > 0; off >>= 1) {
        s0 += __shfl_down(s0, off);
        s1 += __shfl_down(s1, off);
    }
    const int lane = threadIdx.x & 63, w = threadIdx.x >> 6;
    __syncthreads();
    if (lane == 0) { sm[w * 2] = s0; sm[w * 2 + 1] = s1; }
    __syncthreads();
    s0 = sm[0] + sm[2] + sm[4] + sm[6];
    s1 = sm[1] + sm[3] + sm[5] + sm[7];
}

// ---------------- fp32 -> bf16 conversion (large arrays) ----------------
__global__ __launch_bounds__(256) void cvt_bf16(
    const float* __restrict__ s, u16* __restrict__ d, int n)
{
    const int i = (blockIdx.x * 256 + threadIdx.x) * 4;
    if (i >= n) return;
    const float4 v = *reinterpret_cast<const float4*>(s + i);
    ushort4 o = make_ushort4(f2bf(v.x), f2bf(v.y), f2bf(v.z), f2bf(v.w));
    *reinterpret_cast<ushort4*>(d + i) = o;
}

// ---------------- fused multi-array conversion (weights) ----------------
struct CvtJobs {
    const float* s[5];
    u16* d[5];
    int cum[6];   // cumulative quad counts
};
__global__ __launch_bounds__(256) void cvt_multi(CvtJobs j)
{
    const int g = blockIdx.x * 256 + threadIdx.x;   // quad index
    if (g >= j.cum[5]) return;
    int seg = 0;
    #pragma unroll
    for (int k = 1; k < 5; ++k) seg += (g >= j.cum[k]);
    const int q = g - j.cum[seg];
    const float4 v = *reinterpret_cast<const float4*>(j.s[seg] + q * 4);
    ushort4 o = make_ushort4(f2bf(v.x), f2bf(v.y), f2bf(v.z), f2bf(v.w));
    *reinterpret_cast<ushort4*>(j.d[seg] + q * 4) = o;
}

// ---------------- W2 fold: W2 = p1b @ out_w  (fp32 in, bf16 out) ------------
// p1b = p1_w[:, 512:1024]  (A[i,k], ld=1024), out_w row-major [k][j].
// Writes W2 into cols 512..1023 of the combined [512][1024] p1 weight buffer.
__global__ __launch_bounds__(256) void fold_w2(
    const float* __restrict__ p1w, const float* __restrict__ outw,
    u16* __restrict__ p1cb)
{
    __shared__ float As[16][65];   // [k][i]
    __shared__ float Bs[16][65];   // [k][j]
    const int tx = threadIdx.x & 15, ty = threadIdx.x >> 4;
    const int i0 = blockIdx.y * 64, j0 = blockIdx.x * 64;
    const int lr = threadIdx.x >> 2;          // 0..63
    const int lc = (threadIdx.x & 3) * 4;     // 0,4,8,12
    const int kr = threadIdx.x >> 4;          // 0..15
    const int jc = (threadIdx.x & 15) * 4;    // 0..60
    float acc[4][4] = {};
    for (int k0 = 0; k0 < 512; k0 += 16) {
        const float4 av = *reinterpret_cast<const float4*>(
            p1w + (size_t)(i0 + lr) * 1024 + 512 + k0 + lc);
        As[lc + 0][lr] = av.x; As[lc + 1][lr] = av.y;
        As[lc + 2][lr] = av.z; As[lc + 3][lr] = av.w;
        const float4 bv = *reinterpret_cast<const float4*>(
            outw + (size_t)(k0 + kr) * 512 + j0 + jc);
        Bs[kr][jc + 0] = bv.x; Bs[kr][jc + 1] = bv.y;
        Bs[kr][jc + 2] = bv.z; Bs[kr][jc + 3] = bv.w;
        __syncthreads();
        #pragma unroll
        for (int kk = 0; kk < 16; ++kk) {
            float a[4], b[4];
            #pragma unroll
            for (int i = 0; i < 4; ++i) a[i] = As[kk][ty * 4 + i];
            #pragma unroll
            for (int jj = 0; jj < 4; ++jj) b[jj] = Bs[kk][tx * 4 + jj];
            #pragma unroll
            for (int i = 0; i < 4; ++i)
                #pragma unroll
                for (int jj = 0; jj < 4; ++jj)
                    acc[i][jj] = fmaf(a[i], b[jj], acc[i][jj]);
        }
        __syncthreads();
    }
    #pragma unroll
    for (int i = 0; i < 4; ++i)
        #pragma unroll
        for (int jj = 0; jj < 4; ++jj)
            p1cb[(size_t)(i0 + ty * 4 + i) * 1024 + 512 + j0 + tx * 4 + jj] =
                f2bf(acc[i][jj]);
}

// bias2[i] = p1_b[i] + sum_k p1_w[i][512+k] * out_b[k]
__global__ __launch_bounds__(64) void fold_bias(
    const float* __restrict__ p1w, const float* __restrict__ outb,
    const float* __restrict__ p1b, float* __restrict__ bias2)
{
    const int i = blockIdx.x, lane = threadIdx.x;
    float s = 0.0f;
    #pragma unroll
    for (int k = lane; k < 512; k += 64)
        s += p1w[(size_t)i * 1024 + 512 + k] * outb[k];
    #pragma unroll
    for (int off = 32; off > 0; off >>= 1) s += __shfl_down(s, off);
    if (lane == 0) bias2[i] = s + p1b[i];
}

// ---------------- bf16 MFMA GEMM: C[M,N] = A[M,K] @ W[N,K]^T (+bias) --------
// m97 structure: 128x128 tile, BK=32, 4 waves, global_load_lds width-16
// staging into linear [128][32] bf16 LDS, mfma_f32_16x16x32_bf16.
template<bool HAS_A2, bool OUT_BF16>
__global__ __launch_bounds__(256) void gemm_bf16(
    const u16* __restrict__ A1, const u16* __restrict__ A2, int K1, int K,
    const u16* __restrict__ W, const float* __restrict__ bias,
    void* __restrict__ Cv, int N)
{
    __shared__ __bf16 As[128 * 32];
    __shared__ __bf16 Ws[128 * 32];
    const int tid = threadIdx.x;
    const int w = tid >> 6, lane = tid & 63;
    const int row0 = blockIdx.y * 128;
    const int col0 = blockIdx.x * 128;
    const int wr = (w >> 1) * 64, wc = (w & 1) * 64;
    const int fr = lane & 15, fg = lane >> 4;

    int srow[2], scol[2], soff[2];
    #pragma unroll
    for (int c = 0; c < 2; ++c) {
        const int bo = w * 2048 + c * 1024 + lane * 16;
        srow[c] = bo >> 6;
        scol[c] = (bo & 63) >> 1;
        soff[c] = (w * 2048 + c * 1024) >> 1;
    }

    f32x4 acc[4][4] = {};

    for (int k0 = 0; k0 < K; k0 += 32) {
        #pragma unroll
        for (int c = 0; c < 2; ++c) {
            const u16* asrc;
            if (HAS_A2) {
                const bool first = (k0 < K1);
                const u16* base = first ? A1 : A2;
                const int ldk = first ? K1 : (K - K1);
                const int kk  = first ? k0 : (k0 - K1);
                asrc = base + (size_t)(row0 + srow[c]) * ldk + kk + scol[c];
            } else {
                asrc = A1 + (size_t)(row0 + srow[c]) * K + k0 + scol[c];
            }
            __builtin_amdgcn_global_load_lds(
                (const __attribute__((address_space(1))) u32*)asrc,
                (__attribute__((address_space(3))) u32*)(As + soff[c]), 16, 0, 0);
            const u16* wsrc = W + (size_t)(col0 + srow[c]) * K + k0 + scol[c];
            __builtin_amdgcn_global_load_lds(
                (const __attribute__((address_space(1))) u32*)wsrc,
                (__attribute__((address_space(3))) u32*)(Ws + soff[c]), 16, 0, 0);
        }
        __syncthreads();

        bf16x8 af[4], bfr[4];
        #pragma unroll
        for (int m = 0; m < 4; ++m) {
            af[m]  = *(const bf16x8*)(As + (wr + m * 16 + fr) * 32 + fg * 8);
            bfr[m] = *(const bf16x8*)(Ws + (wc + m * 16 + fr) * 32 + fg * 8);
        }
        #pragma unroll
        for (int m = 0; m < 4; ++m)
            #pragma unroll
            for (int n = 0; n < 4; ++n)
                acc[m][n] = __builtin_amdgcn_mfma_f32_16x16x32_bf16(
                    af[m], bfr[n], acc[m][n], 0, 0, 0);
        __syncthreads();
    }

    #pragma unroll
    for (int m = 0; m < 4; ++m) {
        #pragma unroll
        for (int n = 0; n < 4; ++n) {
            const int col = col0 + wc + n * 16 + fr;
            const float bv = bias ? bias[col] : 0.0f;
            #pragma unroll
            for (int r = 0; r < 4; ++r) {
                const int row = row0 + wr + m * 16 + fg * 4 + r;
                const float v = acc[m][n][r] + bv;
                if (OUT_BF16) ((u16*)Cv)[(size_t)row * N + col] = f2bf(v);
                else          ((float*)Cv)[(size_t)row * N + col] = v;
            }
        }
    }
}

// ---------------- Row LayerNorm (fp32 in, bf16 out), 512 cols, opt GELU -----
template<bool GELU>
__global__ __launch_bounds__(256) void ln_rows(
    const float* __restrict__ X, const float* __restrict__ g,
    const float* __restrict__ b, u16* __restrict__ Y)
{
    __shared__ float sm[8];
    const size_t base = (size_t)blockIdx.x * 512;
    const int t = threadIdx.x;
    const float2 x = *reinterpret_cast<const float2*>(X + base + 2 * t);
    float s0 = x.x + x.y, s1 = x.x * x.x + x.y * x.y;
    breduce2(s0, s1, sm);
    const float mu = s0 * (1.0f / 512.0f);
    const float var = s1 * (1.0f / 512.0f) - mu * mu;
    const float rs = rsqrtf(var + 1e-5f);
    const float2 gg = *reinterpret_cast<const float2*>(g + 2 * t);
    const float2 bb = *reinterpret_cast<const float2*>(b + 2 * t);
    float y0 = (x.x - mu) * rs * gg.x + bb.x;
    float y1 = (x.y - mu) * rs * gg.y + bb.y;
    if (GELU) { y0 = gelu_exact(y0); y1 = gelu_exact(y1); }
    *reinterpret_cast<ushort2*>(Y + base + 2 * t) = make_ushort2(f2bf(y0), f2bf(y1));
}

// ---------------- Attention: wave per (line, head); lane = dgroup*8 + m -----
__global__ __launch_bounds__(512) void attn_kernel(
    const u16* __restrict__ qh, const u16* __restrict__ kvb,
    const int* __restrict__ kidx, const int* __restrict__ ncnt,
    u16* __restrict__ ctx)
{
    const int l = blockIdx.x;
    const int head = threadIdx.x >> 6;
    const int lane = threadIdx.x & 63;
    const int mi = lane & 7, dg = lane >> 3;
    const int cnt = ncnt[l];
    const int idx = kidx[l * 8 + mi];

    const u16x8 qv = *(const u16x8*)(qh + (size_t)l * 512 + head * 64 + dg * 8);
    const u16x8 kv = *(const u16x8*)(kvb + (size_t)idx * 1024 + head * 64 + dg * 8);
    float p = 0.0f;
    #pragma unroll
    for (int jj = 0; jj < 8; ++jj) p = fmaf(bf2f(qv[jj]), bf2f(kv[jj]), p);
    p += __shfl_xor(p, 8); p += __shfl_xor(p, 16); p += __shfl_xor(p, 32);

    float s = (mi < cnt) ? p * 0.125f : -3.402823466e38f;
    float mx = s;
    mx = fmaxf(mx, __shfl_xor(mx, 1));
    mx = fmaxf(mx, __shfl_xor(mx, 2));
    mx = fmaxf(mx, __shfl_xor(mx, 4));
    const float e = __expf(s - mx);
    float den = e;
    den += __shfl_xor(den, 1); den += __shfl_xor(den, 2); den += __shfl_xor(den, 4);
    const float wgt = e / den;

    const u16x8 vv = *(const u16x8*)(kvb + (size_t)idx * 1024 + 512 + head * 64 + dg * 8);
    float c[8];
    #pragma unroll
    for (int jj = 0; jj < 8; ++jj) c[jj] = wgt * bf2f(vv[jj]);

    const bool b0 = (mi & 1), b1 = (mi & 2), b2 = (mi & 4);
    #pragma unroll
    for (int jj = 0; jj < 4; ++jj) {
        const float snd = b0 ? c[jj] : c[jj + 4];
        const float rec = __shfl_xor(snd, 1);
        c[jj] = (b0 ? c[jj + 4] : c[jj]) + rec;
    }
    #pragma unroll
    for (int jj = 0; jj < 2; ++jj) {
        const float snd = b1 ? c[jj] : c[jj + 2];
        const float rec = __shfl_xor(snd, 2);
        c[jj] = (b1 ? c[jj + 2] : c[jj]) + rec;
    }
    {
        const float snd = b2 ? c[0] : c[1];
        const float rec = __shfl_xor(snd, 4);
        c[0] = (b2 ? c[1] : c[0]) + rec;
    }
    const int doff = (b0 ? 4 : 0) + (b1 ? 2 : 0) + (b2 ? 1 : 0);
    ctx[(size_t)l * 512 + head * 64 + dg * 8 + doff] = f2bf(c[0]);
}

// ---------------- Final: h2 = h1 + gelu(LN(h2_raw)); sigmoid(head) ----------
__global__ __launch_bounds__(256) void final_head(
    const u16* __restrict__ h1, const float* __restrict__ h2raw,
    const float* __restrict__ g, const float* __restrict__ b,
    const float* __restrict__ hw, const float* __restrict__ hb,
    float* __restrict__ out)
{
    __shared__ float sm[8];
    const size_t base = (size_t)blockIdx.x * 512;
    const int t = threadIdx.x;
    const float2 x = *reinterpret_cast<const float2*>(h2raw + base + 2 * t);
    float s0 = x.x + x.y, s1 = x.x * x.x + x.y * x.y;
    breduce2(s0, s1, sm);
    const float mu = s0 * (1.0f / 512.0f);
    const float var = s1 * (1.0f / 512.0f) - mu * mu;
    const float rs = rsqrtf(var + 1e-5f);
    const float2 gg = *reinterpret_cast<const float2*>(g + 2 * t);
    const float2 bb = *reinterpret_cast<const float2*>(b + 2 * t);
    const ushort2 h = *reinterpret_cast<const ushort2*>(h1 + base + 2 * t);
    const float2 hwv = *reinterpret_cast<const float2*>(hw + 2 * t);
    const float y0 = bf2f(h.x) + gelu_exact((x.x - mu) * rs * gg.x + bb.x);
    const float y1 = bf2f(h.y) + gelu_exact((x.y - mu) * rs * gg.y + bb.y);
    float d0 = y0 * hwv.x + y1 * hwv.y, d1 = 0.0f;
    breduce2(d0, d1, sm);
    if (t == 0) out[blockIdx.x] = 1.0f / (1.0f + expf(-(d0 + hb[0])));
}

extern "C" void kernel_launch(void* const* d_in, const int* in_sizes, int n_in,
                              void* d_out, int out_size, void* d_ws, size_t ws_size,
                              hipStream_t stream)
{
    const float* lines  = (const float*)d_in[0];   // [32768,768]
    const float* blocks = (const float*)d_in[1];   // [8192,768]
    const float* Wq     = (const float*)d_in[2];   // [512,768]
    const float* Wkv    = (const float*)d_in[3];   // [512,768]
    const float* qn_g   = (const float*)d_in[4];
    const float* qn_b   = (const float*)d_in[5];
    const float* kvn_g  = (const float*)d_in[6];
    const float* kvn_b  = (const float*)d_in[7];
    const float* in_w   = (const float*)d_in[8];   // [1536,512]
    const float* in_b   = (const float*)d_in[9];   // [1536]
    const float* out_w  = (const float*)d_in[10];  // [512,512]
    const float* out_b  = (const float*)d_in[11];
    const float* p1_w   = (const float*)d_in[12];  // [512,1024]
    const float* p1_b   = (const float*)d_in[13];
    const float* ln1_g  = (const float*)d_in[14];
    const float* ln1_b  = (const float*)d_in[15];
    const float* p2_w   = (const float*)d_in[16];  // [512,512]
    const float* p2_b   = (const float*)d_in[17];
    const float* ln2_g  = (const float*)d_in[18];
    const float* ln2_b  = (const float*)d_in[19];
    const float* head_w = (const float*)d_in[20];  // [1,512]
    const float* head_b = (const float*)d_in[21];  // [1]
    const int*   kidx   = (const int*)d_in[22];    // [32768,8]
    const int*   ncnt   = (const int*)d_in[23];    // [32768]
    float* out = (float*)d_out;                    // [32768]

    char* wsb = (char*)d_ws;
    float* Sf   = (float*)(wsb);                    // fp32 scratch [0,64M)
    float* bkvf = Sf;
    u16* Bb     = (u16*)(wsb + (16ull << 20));      // bf16 blocks (dead before Sf full write)
    u16* qb     = (u16*)(wsb + (64ull << 20));
    u16* qhb    = (u16*)(wsb + (96ull << 20));
    u16* Lb     = (u16*)(wsb + (96ull << 20));      // bf16 lines (dead before qhb)
    u16* ctxb   = (u16*)(wsb + (128ull << 20));
    u16* kvbb   = (u16*)(wsb + (160ull << 20));
    u16* bkvb   = (u16*)(wsb + (176ull << 20));
    u16* Wqb    = (u16*)(wsb + (184ull << 20));
    u16* Wkvb   = Wqb + 512 * 768;
    u16* inwb   = Wkvb + 512 * 768;
    u16* p1cb   = inwb + 1536 * 512;                // [512][1024] combined p1a|W2
    u16* p2wb   = p1cb + 512 * 1024;
    float* bias2f = (float*)(p2wb + 512 * 512);

    // activations to bf16
    cvt_bf16<<<(32768 * 768 / 4 + 255) / 256, 256, 0, stream>>>(lines, Lb, 32768 * 768);
    cvt_bf16<<<(8192 * 768 / 4 + 255) / 256, 256, 0, stream>>>(blocks, Bb, 8192 * 768);
    // weights: one fused launch (p1_w converted fully; cols 512.. overwritten by fold_w2)
    {
        CvtJobs j;
        const float* ss[5] = { Wq, Wkv, in_w, p1_w, p2_w };
        u16* dd[5] = { Wqb, Wkvb, inwb, p1cb, p2wb };
        const int nn[5] = { 512 * 768, 512 * 768, 1536 * 512, 512 * 1024, 512 * 512 };
        int c = 0;
        for (int k = 0; k < 5; ++k) { j.s[k] = ss[k]; j.d[k] = dd[k]; j.cum[k] = c; c += nn[k] / 4; }
        j.cum[5] = c;
        cvt_multi<<<(c + 255) / 256, 256, 0, stream>>>(j);
    }
    // fold out-proj into p1:  W2 = p1b @ out_w  -> p1cb cols 512..1023
    fold_w2<<<dim3(8, 8), 256, 0, stream>>>(p1_w, out_w, p1cb);
    fold_bias<<<512, 64, 0, stream>>>(p1_w, out_b, p1_b, bias2f);

    // 1. bkv_raw = blocks @ Wkv^T                 [8192,512] fp32
    gemm_bf16<false, false><<<dim3(4, 64), 256, 0, stream>>>(
        Bb, nullptr, 768, 768, Wkvb, nullptr, bkvf, 512);
    // 2. bkvb = LN(bkv_raw)                       bf16
    ln_rows<false><<<8192, 256, 0, stream>>>(bkvf, kvn_g, kvn_b, bkvb);
    // 3. kvbb = bkvb @ [wk;wv]^T + [bk;bv]        [8192,1024] bf16
    gemm_bf16<false, true><<<dim3(8, 64), 256, 0, stream>>>(
        bkvb, nullptr, 512, 512, inwb + 512 * 512, in_b + 512, kvbb, 1024);
    // 4. q_raw = lines @ Wq^T                     [32768,512] fp32
    gemm_bf16<false, false><<<dim3(4, 256), 256, 0, stream>>>(
        Lb, nullptr, 768, 768, Wqb, nullptr, Sf, 512);
    // 5. qb = LN(q_raw)                           bf16
    ln_rows<false><<<32768, 256, 0, stream>>>(Sf, qn_g, qn_b, qb);
    // 6. qhb = qb @ wq_i^T + bq_i                 [32768,512] bf16
    gemm_bf16<false, true><<<dim3(4, 256), 256, 0, stream>>>(
        qb, nullptr, 512, 512, inwb, in_b, qhb, 512);
    // 7. ctxb (attention)
    attn_kernel<<<32768, 512, 0, stream>>>(qhb, kvbb, kidx, ncnt, ctxb);
    // 8. h1_raw = qb@p1a^T + ctxb@W2^T + bias2    [32768,512] fp32  (out-proj folded)
    gemm_bf16<true, false><<<dim3(4, 256), 256, 0, stream>>>(
        qb, ctxb, 512, 1024, p1cb, bias2f, Sf, 512);
    // 9. h1 = gelu(LN(h1_raw))  bf16 into ctxb (ctx dead)
    ln_rows<true><<<32768, 256, 0, stream>>>(Sf, ln1_g, ln1_b, ctxb);
    // 10. h2_raw = h1 @ p2_w^T + p2_b             [32768,512] fp32
    gemm_bf16<false, false><<<dim3(4, 256), 256, 0, stream>>>(
        ctxb, nullptr, 512, 512, p2wb, p2_b, Sf, 512);
    // 11. out = sigmoid((h1 + gelu(LN(h2_raw))) . head_w + head_b)
    final_head<<<32768, 256, 0, stream>>>(ctxb, Sf, ln2_g, ln2_b, head_w, head_b, out);
}

// Round 6
// 483.252 us; speedup vs baseline: 1.3238x; 1.0857x over previous
//
#include <hip/hip_runtime.h>
#include <math.h>

// L=32768 lines, M=8 neighbors, B=8192 blocks, LIN=BIN=768, H=512, NH=8, DH=64

typedef unsigned short u16;
typedef unsigned int u32;
using bf16x8 = __attribute__((ext_vector_type(8))) __bf16;
using u16x8  = __attribute__((ext_vector_type(8))) u16;
using f32x4  = __attribute__((ext_vector_type(4))) float;

__device__ __forceinline__ u16 f2bf(float f) {
    u32 u = __builtin_bit_cast(u32, f);
    u32 r = u + 0x7fffu + ((u >> 16) & 1u);
    return (u16)(r >> 16);
}
__device__ __forceinline__ float bf2f(u16 h) {
    return __builtin_bit_cast(float, (u32)h << 16);
}
__device__ __forceinline__ float gelu_exact(float x) {
    return 0.5f * x * (1.0f + erff(x * 0.70710678118654752440f));
}

// Block-wide reduction of one value across 256 threads (4 waves).
__device__ __forceinline__ float breduce1(float s0, float* sm) {
    #pragma unroll
    for (int off = 32; off > 0; off >>= 1) s0 += __shfl_down(s0, off);
    const int lane = threadIdx.x & 63, w = threadIdx.x >> 6;
    __syncthreads();
    if (lane == 0) sm[w] = s0;
    __syncthreads();
    return sm[0] + sm[1] + sm[2] + sm[3];
}

// ---------------- fp32 -> bf16 conversion (large arrays) ----------------
__global__ __launch_bounds__(256) void cvt_bf16(
    const float* __restrict__ s, u16* __restrict__ d, int n)
{
    const int i = (blockIdx.x * 256 + threadIdx.x) * 4;
    if (i >= n) return;
    const float4 v = *reinterpret_cast<const float4*>(s + i);
    ushort4 o = make_ushort4(f2bf(v.x), f2bf(v.y), f2bf(v.z), f2bf(v.w));
    *reinterpret_cast<ushort4*>(d + i) = o;
}

// ---------------- fused multi-array conversion (weights) ----------------
struct CvtJobs {
    const float* s[5];
    u16* d[5];
    int cum[6];   // cumulative quad counts
};
__global__ __launch_bounds__(256) void cvt_multi(CvtJobs j)
{
    const int g = blockIdx.x * 256 + threadIdx.x;   // quad index
    if (g >= j.cum[5]) return;
    int seg = 0;
    #pragma unroll
    for (int k = 1; k < 5; ++k) seg += (g >= j.cum[k]);
    const int q = g - j.cum[seg];
    const float4 v = *reinterpret_cast<const float4*>(j.s[seg] + q * 4);
    ushort4 o = make_ushort4(f2bf(v.x), f2bf(v.y), f2bf(v.z), f2bf(v.w));
    *reinterpret_cast<ushort4*>(j.d[seg] + q * 4) = o;
}

// ---------------- W2 fold: W2 = p1b @ out_w  (fp32 in, bf16 out) ------------
__global__ __launch_bounds__(256) void fold_w2(
    const float* __restrict__ p1w, const float* __restrict__ outw,
    u16* __restrict__ p1cb)
{
    __shared__ float As[16][65];   // [k][i]
    __shared__ float Bs[16][65];   // [k][j]
    const int tx = threadIdx.x & 15, ty = threadIdx.x >> 4;
    const int i0 = blockIdx.y * 64, j0 = blockIdx.x * 64;
    const int lr = threadIdx.x >> 2;
    const int lc = (threadIdx.x & 3) * 4;
    const int kr = threadIdx.x >> 4;
    const int jc = (threadIdx.x & 15) * 4;
    float acc[4][4] = {};
    for (int k0 = 0; k0 < 512; k0 += 16) {
        const float4 av = *reinterpret_cast<const float4*>(
            p1w + (size_t)(i0 + lr) * 1024 + 512 + k0 + lc);
        As[lc + 0][lr] = av.x; As[lc + 1][lr] = av.y;
        As[lc + 2][lr] = av.z; As[lc + 3][lr] = av.w;
        const float4 bv = *reinterpret_cast<const float4*>(
            outw + (size_t)(k0 + kr) * 512 + j0 + jc);
        Bs[kr][jc + 0] = bv.x; Bs[kr][jc + 1] = bv.y;
        Bs[kr][jc + 2] = bv.z; Bs[kr][jc + 3] = bv.w;
        __syncthreads();
        #pragma unroll
        for (int kk = 0; kk < 16; ++kk) {
            float a[4], b[4];
            #pragma unroll
            for (int i = 0; i < 4; ++i) a[i] = As[kk][ty * 4 + i];
            #pragma unroll
            for (int jj = 0; jj < 4; ++jj) b[jj] = Bs[kk][tx * 4 + jj];
            #pragma unroll
            for (int i = 0; i < 4; ++i)
                #pragma unroll
                for (int jj = 0; jj < 4; ++jj)
                    acc[i][jj] = fmaf(a[i], b[jj], acc[i][jj]);
        }
        __syncthreads();
    }
    #pragma unroll
    for (int i = 0; i < 4; ++i)
        #pragma unroll
        for (int jj = 0; jj < 4; ++jj)
            p1cb[(size_t)(i0 + ty * 4 + i) * 1024 + 512 + j0 + tx * 4 + jj] =
                f2bf(acc[i][jj]);
}

// bias2[i] = p1_b[i] + sum_k p1_w[i][512+k] * out_b[k]
__global__ __launch_bounds__(64) void fold_bias(
    const float* __restrict__ p1w, const float* __restrict__ outb,
    const float* __restrict__ p1b, float* __restrict__ bias2)
{
    const int i = blockIdx.x, lane = threadIdx.x;
    float s = 0.0f;
    #pragma unroll
    for (int k = lane; k < 512; k += 64)
        s += p1w[(size_t)i * 1024 + 512 + k] * outb[k];
    #pragma unroll
    for (int off = 32; off > 0; off >>= 1) s += __shfl_down(s, off);
    if (lane == 0) bias2[i] = s + p1b[i];
}

// ---------------- bf16 MFMA GEMM: C[M,N] = A[M,K] @ W[N,K]^T (+bias) --------
// m97 structure: 128x128 tile, BK=32, 4 waves, global_load_lds width-16.
// STATS: also emit per-64-col partial row (sum,sumsq) into stats[row][8]
// (float2); requires N==512 (grid.x==4).
template<bool HAS_A2, bool STATS>
__global__ __launch_bounds__(256) void gemm_bf16(
    const u16* __restrict__ A1, const u16* __restrict__ A2, int K1, int K,
    const u16* __restrict__ W, const float* __restrict__ bias,
    u16* __restrict__ C, int N, float* __restrict__ stats)
{
    __shared__ __bf16 As[128 * 32];
    __shared__ __bf16 Ws[128 * 32];
    const int tid = threadIdx.x;
    const int w = tid >> 6, lane = tid & 63;
    const int row0 = blockIdx.y * 128;
    const int col0 = blockIdx.x * 128;
    const int wr = (w >> 1) * 64, wc = (w & 1) * 64;
    const int fr = lane & 15, fg = lane >> 4;

    int srow[2], scol[2], soff[2];
    #pragma unroll
    for (int c = 0; c < 2; ++c) {
        const int bo = w * 2048 + c * 1024 + lane * 16;
        srow[c] = bo >> 6;
        scol[c] = (bo & 63) >> 1;
        soff[c] = (w * 2048 + c * 1024) >> 1;
    }

    f32x4 acc[4][4] = {};

    for (int k0 = 0; k0 < K; k0 += 32) {
        #pragma unroll
        for (int c = 0; c < 2; ++c) {
            const u16* asrc;
            if (HAS_A2) {
                const bool first = (k0 < K1);
                const u16* base = first ? A1 : A2;
                const int ldk = first ? K1 : (K - K1);
                const int kk  = first ? k0 : (k0 - K1);
                asrc = base + (size_t)(row0 + srow[c]) * ldk + kk + scol[c];
            } else {
                asrc = A1 + (size_t)(row0 + srow[c]) * K + k0 + scol[c];
            }
            __builtin_amdgcn_global_load_lds(
                (const __attribute__((address_space(1))) u32*)asrc,
                (__attribute__((address_space(3))) u32*)(As + soff[c]), 16, 0, 0);
            const u16* wsrc = W + (size_t)(col0 + srow[c]) * K + k0 + scol[c];
            __builtin_amdgcn_global_load_lds(
                (const __attribute__((address_space(1))) u32*)wsrc,
                (__attribute__((address_space(3))) u32*)(Ws + soff[c]), 16, 0, 0);
        }
        __syncthreads();

        bf16x8 af[4], bfr[4];
        #pragma unroll
        for (int m = 0; m < 4; ++m) {
            af[m]  = *(const bf16x8*)(As + (wr + m * 16 + fr) * 32 + fg * 8);
            bfr[m] = *(const bf16x8*)(Ws + (wc + m * 16 + fr) * 32 + fg * 8);
        }
        #pragma unroll
        for (int m = 0; m < 4; ++m)
            #pragma unroll
            for (int n = 0; n < 4; ++n)
                acc[m][n] = __builtin_amdgcn_mfma_f32_16x16x32_bf16(
                    af[m], bfr[n], acc[m][n], 0, 0, 0);
        __syncthreads();
    }

    // bias add (pre-stats, pre-round)
    if (bias) {
        #pragma unroll
        for (int n = 0; n < 4; ++n) {
            const float bv = bias[col0 + wc + n * 16 + fr];
            #pragma unroll
            for (int m = 0; m < 4; ++m)
                #pragma unroll
                for (int r = 0; r < 4; ++r)
                    acc[m][n][r] += bv;
        }
    }

    // C/D layout: col=lane&15, row=(lane>>4)*4+reg  [m89-verified]
    #pragma unroll
    for (int m = 0; m < 4; ++m)
        #pragma unroll
        for (int n = 0; n < 4; ++n) {
            const int col = col0 + wc + n * 16 + fr;
            #pragma unroll
            for (int r = 0; r < 4; ++r) {
                const int row = row0 + wr + m * 16 + fg * 4 + r;
                C[(size_t)row * N + col] = f2bf(acc[m][n][r]);
            }
        }

    if (STATS) {
        float ps[4][4], pq[4][4];
        #pragma unroll
        for (int m = 0; m < 4; ++m)
            #pragma unroll
            for (int r = 0; r < 4; ++r) {
                float s = 0.0f, q2 = 0.0f;
                #pragma unroll
                for (int n = 0; n < 4; ++n) {
                    const float v = acc[m][n][r];
                    s += v; q2 = fmaf(v, v, q2);
                }
                ps[m][r] = s; pq[m][r] = q2;
            }
        #pragma unroll
        for (int off = 1; off < 16; off <<= 1)
            #pragma unroll
            for (int m = 0; m < 4; ++m)
                #pragma unroll
                for (int r = 0; r < 4; ++r) {
                    ps[m][r] += __shfl_xor(ps[m][r], off);
                    pq[m][r] += __shfl_xor(pq[m][r], off);
                }
        if (fr == 0) {
            const int cb = blockIdx.x * 2 + (w & 1);
            #pragma unroll
            for (int m = 0; m < 4; ++m)
                #pragma unroll
                for (int r = 0; r < 4; ++r) {
                    const int row = row0 + wr + m * 16 + fg * 4 + r;
                    *reinterpret_cast<float2*>(stats + ((size_t)row * 8 + cb) * 2) =
                        make_float2(ps[m][r], pq[m][r]);
                }
        }
    }
}

// ---------------- Row LayerNorm in-place (bf16 x + precomputed stats) -------
template<bool GELU>
__global__ __launch_bounds__(256) void ln_rows_s(
    u16* __restrict__ X, const float* __restrict__ stats,
    const float* __restrict__ g, const float* __restrict__ b)
{
    const size_t row = blockIdx.x;
    float s = 0.0f, q2 = 0.0f;
    #pragma unroll
    for (int cb = 0; cb < 8; ++cb) {
        s  += stats[(row * 8 + cb) * 2];
        q2 += stats[(row * 8 + cb) * 2 + 1];
    }
    const float mu = s * (1.0f / 512.0f);
    const float var = q2 * (1.0f / 512.0f) - mu * mu;
    const float rs = rsqrtf(var + 1e-5f);
    const int t = threadIdx.x;
    const ushort2 xv = *reinterpret_cast<const ushort2*>(X + row * 512 + 2 * t);
    const float2 gg = *reinterpret_cast<const float2*>(g + 2 * t);
    const float2 bb = *reinterpret_cast<const float2*>(b + 2 * t);
    float y0 = (bf2f(xv.x) - mu) * rs * gg.x + bb.x;
    float y1 = (bf2f(xv.y) - mu) * rs * gg.y + bb.y;
    if (GELU) { y0 = gelu_exact(y0); y1 = gelu_exact(y1); }
    *reinterpret_cast<ushort2*>(X + row * 512 + 2 * t) = make_ushort2(f2bf(y0), f2bf(y1));
}

// ---------------- Attention: persistent, wave per (line, head) ----------
__global__ __launch_bounds__(512) void attn_kernel(
    const u16* __restrict__ qh, const u16* __restrict__ kvb,
    const int* __restrict__ kidx, const int* __restrict__ ncnt,
    u16* __restrict__ ctx)
{
    const int head = threadIdx.x >> 6;
    const int lane = threadIdx.x & 63;
    const int mi = lane & 7, dg = lane >> 3;
    const bool b0 = (mi & 1), b1 = (mi & 2), b2 = (mi & 4);
    const int doff = (b0 ? 4 : 0) + (b1 ? 2 : 0) + (b2 ? 1 : 0);

    for (int l = blockIdx.x; l < 32768; l += gridDim.x) {
        const int cnt = ncnt[l];
        const int idx = kidx[l * 8 + mi];
        const size_t kvbase = (size_t)idx * 1024 + head * 64 + dg * 8;

        const u16x8 qv = *(const u16x8*)(qh + (size_t)l * 512 + head * 64 + dg * 8);
        const u16x8 kv = *(const u16x8*)(kvb + kvbase);
        const u16x8 vv = *(const u16x8*)(kvb + kvbase + 512);   // early V load

        float p = 0.0f;
        #pragma unroll
        for (int jj = 0; jj < 8; ++jj) p = fmaf(bf2f(qv[jj]), bf2f(kv[jj]), p);
        p += __shfl_xor(p, 8); p += __shfl_xor(p, 16); p += __shfl_xor(p, 32);

        float s = (mi < cnt) ? p * 0.125f : -3.402823466e38f;
        float mx = s;
        mx = fmaxf(mx, __shfl_xor(mx, 1));
        mx = fmaxf(mx, __shfl_xor(mx, 2));
        mx = fmaxf(mx, __shfl_xor(mx, 4));
        const float e = __expf(s - mx);
        float den = e;
        den += __shfl_xor(den, 1); den += __shfl_xor(den, 2); den += __shfl_xor(den, 4);
        const float wgt = e / den;

        float c[8];
        #pragma unroll
        for (int jj = 0; jj < 8; ++jj) c[jj] = wgt * bf2f(vv[jj]);

        #pragma unroll
        for (int jj = 0; jj < 4; ++jj) {
            const float snd = b0 ? c[jj] : c[jj + 4];
            const float rec = __shfl_xor(snd, 1);
            c[jj] = (b0 ? c[jj + 4] : c[jj]) + rec;
        }
        #pragma unroll
        for (int jj = 0; jj < 2; ++jj) {
            const float snd = b1 ? c[jj] : c[jj + 2];
            const float rec = __shfl_xor(snd, 2);
            c[jj] = (b1 ? c[jj + 2] : c[jj]) + rec;
        }
        {
            const float snd = b2 ? c[0] : c[1];
            const float rec = __shfl_xor(snd, 4);
            c[0] = (b2 ? c[1] : c[0]) + rec;
        }
        ctx[(size_t)l * 512 + head * 64 + dg * 8 + doff] = f2bf(c[0]);
    }
}

// ---------------- Final: h2 = h1 + gelu(LN(h2_raw)); sigmoid(head) ----------
__global__ __launch_bounds__(256) void final_head_s(
    const u16* __restrict__ h1, const u16* __restrict__ h2raw,
    const float* __restrict__ stats,
    const float* __restrict__ g, const float* __restrict__ b,
    const float* __restrict__ hw, const float* __restrict__ hb,
    float* __restrict__ out)
{
    __shared__ float sm[4];
    const size_t row = blockIdx.x;
    float s = 0.0f, q2 = 0.0f;
    #pragma unroll
    for (int cb = 0; cb < 8; ++cb) {
        s  += stats[(row * 8 + cb) * 2];
        q2 += stats[(row * 8 + cb) * 2 + 1];
    }
    const float mu = s * (1.0f / 512.0f);
    const float var = q2 * (1.0f / 512.0f) - mu * mu;
    const float rs = rsqrtf(var + 1e-5f);
    const int t = threadIdx.x;
    const ushort2 xv = *reinterpret_cast<const ushort2*>(h2raw + row * 512 + 2 * t);
    const ushort2 hv = *reinterpret_cast<const ushort2*>(h1 + row * 512 + 2 * t);
    const float2 gg = *reinterpret_cast<const float2*>(g + 2 * t);
    const float2 bb = *reinterpret_cast<const float2*>(b + 2 * t);
    const float2 hwv = *reinterpret_cast<const float2*>(hw + 2 * t);
    const float y0 = bf2f(hv.x) + gelu_exact((bf2f(xv.x) - mu) * rs * gg.x + bb.x);
    const float y1 = bf2f(hv.y) + gelu_exact((bf2f(xv.y) - mu) * rs * gg.y + bb.y);
    const float d = breduce1(y0 * hwv.x + y1 * hwv.y, sm);
    if (t == 0) out[row] = 1.0f / (1.0f + expf(-(d + hb[0])));
}

extern "C" void kernel_launch(void* const* d_in, const int* in_sizes, int n_in,
                              void* d_out, int out_size, void* d_ws, size_t ws_size,
                              hipStream_t stream)
{
    const float* lines  = (const float*)d_in[0];   // [32768,768]
    const float* blocks = (const float*)d_in[1];   // [8192,768]
    const float* Wq     = (const float*)d_in[2];   // [512,768]
    const float* Wkv    = (const float*)d_in[3];   // [512,768]
    const float* qn_g   = (const float*)d_in[4];
    const float* qn_b   = (const float*)d_in[5];
    const float* kvn_g  = (const float*)d_in[6];
    const float* kvn_b  = (const float*)d_in[7];
    const float* in_w   = (const float*)d_in[8];   // [1536,512]
    const float* in_b   = (const float*)d_in[9];   // [1536]
    const float* out_w  = (const float*)d_in[10];  // [512,512]
    const float* out_b  = (const float*)d_in[11];
    const float* p1_w   = (const float*)d_in[12];  // [512,1024]
    const float* p1_b   = (const float*)d_in[13];
    const float* ln1_g  = (const float*)d_in[14];
    const float* ln1_b  = (const float*)d_in[15];
    const float* p2_w   = (const float*)d_in[16];  // [512,512]
    const float* p2_b   = (const float*)d_in[17];
    const float* ln2_g  = (const float*)d_in[18];
    const float* ln2_b  = (const float*)d_in[19];
    const float* head_w = (const float*)d_in[20];  // [1,512]
    const float* head_b = (const float*)d_in[21];  // [1]
    const int*   kidx   = (const int*)d_in[22];    // [32768,8]
    const int*   ncnt   = (const int*)d_in[23];    // [32768]
    float* out = (float*)d_out;                    // [32768]

    // workspace layout (liveness-checked):
    //  0M   qb    [32768,512] bf16   q_raw -> q
    //  32M  qhb   [32768,512] bf16   qh -> h1_raw -> h1
    //  64M  ctxb  [32768,512] bf16   ctx -> h2_raw
    //  96M  kvbb  [8192,1024] bf16
    //  112M bkvb  [8192,512]  bf16   bkv_raw -> bkv
    //  120M Lb    [32768,768] bf16 (dead after gemm4) / stats_h1+h2 after
    //  168M Bb    [8192,768]  bf16 (dead after gemm1)
    //  180M weights (~4.5M)
    //  185M stats_q 2M ; 187M stats_bkv 0.5M ; 187.5M bias2
    char* wsb = (char*)d_ws;
    u16* qb    = (u16*)(wsb);
    u16* qhb   = (u16*)(wsb + (32ull << 20));
    u16* ctxb  = (u16*)(wsb + (64ull << 20));
    u16* kvbb  = (u16*)(wsb + (96ull << 20));
    u16* bkvb  = (u16*)(wsb + (112ull << 20));
    u16* Lb    = (u16*)(wsb + (120ull << 20));
    float* stats_h1 = (float*)(wsb + (120ull << 20));   // after Lb dead
    float* stats_h2 = (float*)(wsb + (124ull << 20));
    u16* Bb    = (u16*)(wsb + (168ull << 20));
    u16* Wqb   = (u16*)(wsb + (180ull << 20));
    u16* Wkvb  = Wqb + 512 * 768;
    u16* inwb  = Wkvb + 512 * 768;
    u16* p1cb  = inwb + 1536 * 512;                // [512][1024] combined p1a|W2
    u16* p2wb  = p1cb + 512 * 1024;
    float* stats_q   = (float*)(wsb + (185ull << 20));
    float* stats_bkv = (float*)(wsb + (187ull << 20));
    float* bias2f    = (float*)(wsb + (187ull << 20) + (512ull << 10));

    // activations to bf16
    cvt_bf16<<<(32768 * 768 / 4 + 255) / 256, 256, 0, stream>>>(lines, Lb, 32768 * 768);
    cvt_bf16<<<(8192 * 768 / 4 + 255) / 256, 256, 0, stream>>>(blocks, Bb, 8192 * 768);
    // weights: one fused launch (p1 cols 512.. overwritten by fold_w2)
    {
        CvtJobs j;
        const float* ss[5] = { Wq, Wkv, in_w, p1_w, p2_w };
        u16* dd[5] = { Wqb, Wkvb, inwb, p1cb, p2wb };
        const int nn[5] = { 512 * 768, 512 * 768, 1536 * 512, 512 * 1024, 512 * 512 };
        int c = 0;
        for (int k = 0; k < 5; ++k) { j.s[k] = ss[k]; j.d[k] = dd[k]; j.cum[k] = c; c += nn[k] / 4; }
        j.cum[5] = c;
        cvt_multi<<<(c + 255) / 256, 256, 0, stream>>>(j);
    }
    // fold out-proj into p1
    fold_w2<<<dim3(8, 8), 256, 0, stream>>>(p1_w, out_w, p1cb);
    fold_bias<<<512, 64, 0, stream>>>(p1_w, out_b, p1_b, bias2f);

    // 1. bkv_raw = blocks @ Wkv^T  (bf16 + stats)        [8192,512]
    gemm_bf16<false, true><<<dim3(4, 64), 256, 0, stream>>>(
        Bb, nullptr, 768, 768, Wkvb, nullptr, bkvb, 512, stats_bkv);
    // 2. bkv = LN(bkv_raw) in-place
    ln_rows_s<false><<<8192, 256, 0, stream>>>(bkvb, stats_bkv, kvn_g, kvn_b);
    // 3. kvbb = bkv @ [wk;wv]^T + [bk;bv]                [8192,1024]
    gemm_bf16<false, false><<<dim3(8, 64), 256, 0, stream>>>(
        bkvb, nullptr, 512, 512, inwb + 512 * 512, in_b + 512, kvbb, 1024, nullptr);
    // 4. q_raw = lines @ Wq^T  (bf16 + stats)            [32768,512]
    gemm_bf16<false, true><<<dim3(4, 256), 256, 0, stream>>>(
        Lb, nullptr, 768, 768, Wqb, nullptr, qb, 512, stats_q);
    // 5. q = LN(q_raw) in-place
    ln_rows_s<false><<<32768, 256, 0, stream>>>(qb, stats_q, qn_g, qn_b);
    // 6. qh = q @ wq_i^T + bq_i                          [32768,512]
    gemm_bf16<false, false><<<dim3(4, 256), 256, 0, stream>>>(
        qb, nullptr, 512, 512, inwb, in_b, qhb, 512, nullptr);
    // 7. ctx (attention, persistent grid)
    attn_kernel<<<2048, 512, 0, stream>>>(qhb, kvbb, kidx, ncnt, ctxb);
    // 8. h1_raw = q@p1a^T + ctx@W2^T + bias2  (into qhb; qh dead)  + stats
    gemm_bf16<true, true><<<dim3(4, 256), 256, 0, stream>>>(
        qb, ctxb, 512, 1024, p1cb, bias2f, qhb, 512, stats_h1);
    // 9. h1 = gelu(LN(h1_raw)) in-place
    ln_rows_s<true><<<32768, 256, 0, stream>>>(qhb, stats_h1, ln1_g, ln1_b);
    // 10. h2_raw = h1 @ p2_w^T + p2_b  (into ctxb; ctx dead)  + stats
    gemm_bf16<false, true><<<dim3(4, 256), 256, 0, stream>>>(
        qhb, nullptr, 512, 512, p2wb, p2_b, ctxb, 512, stats_h2);
    // 11. out = sigmoid((h1 + gelu(LN(h2_raw))) . head_w + head_b)
    final_head_s<<<32768, 256, 0, stream>>>(qhb, ctxb, stats_h2, ln2_g, ln2_b,
                                            head_w, head_b, out);
}

// Round 7
// 467.174 us; speedup vs baseline: 1.3694x; 1.0344x over previous
//
#include <hip/hip_runtime.h>
#include <math.h>

// L=32768 lines, M=8 neighbors, B=8192 blocks, LIN=BIN=768, H=512, NH=8, DH=64

typedef unsigned short u16;
typedef unsigned int u32;
using bf16x8 = __attribute__((ext_vector_type(8))) __bf16;
using u16x8  = __attribute__((ext_vector_type(8))) u16;
using f32x4  = __attribute__((ext_vector_type(4))) float;

__device__ __forceinline__ u16 f2bf(float f) {
    u32 u = __builtin_bit_cast(u32, f);
    u32 r = u + 0x7fffu + ((u >> 16) & 1u);
    return (u16)(r >> 16);
}
__device__ __forceinline__ float bf2f(u16 h) {
    return __builtin_bit_cast(float, (u32)h << 16);
}
__device__ __forceinline__ float gelu_exact(float x) {
    return 0.5f * x * (1.0f + erff(x * 0.70710678118654752440f));
}

// Block-wide reduction of one value across 256 threads (4 waves).
__device__ __forceinline__ float breduce1(float s0, float* sm) {
    #pragma unroll
    for (int off = 32; off > 0; off >>= 1) s0 += __shfl_down(s0, off);
    const int lane = threadIdx.x & 63, w = threadIdx.x >> 6;
    __syncthreads();
    if (lane == 0) sm[w] = s0;
    __syncthreads();
    return sm[0] + sm[1] + sm[2] + sm[3];
}

// ---------------- fused multi-array conversion (weights) ----------------
struct CvtJobs {
    const float* s[5];
    u16* d[5];
    int cum[6];   // cumulative quad counts
};
__global__ __launch_bounds__(256) void cvt_multi(CvtJobs j)
{
    const int g = blockIdx.x * 256 + threadIdx.x;   // quad index
    if (g >= j.cum[5]) return;
    int seg = 0;
    #pragma unroll
    for (int k = 1; k < 5; ++k) seg += (g >= j.cum[k]);
    const int q = g - j.cum[seg];
    const float4 v = *reinterpret_cast<const float4*>(j.s[seg] + q * 4);
    ushort4 o = make_ushort4(f2bf(v.x), f2bf(v.y), f2bf(v.z), f2bf(v.w));
    *reinterpret_cast<ushort4*>(j.d[seg] + q * 4) = o;
}

// ---------------- W2 fold: W2 = p1b @ out_w  (fp32 in, bf16 out) ------------
__global__ __launch_bounds__(256) void fold_w2(
    const float* __restrict__ p1w, const float* __restrict__ outw,
    u16* __restrict__ p1cb)
{
    __shared__ float As[16][65];   // [k][i]
    __shared__ float Bs[16][65];   // [k][j]
    const int tx = threadIdx.x & 15, ty = threadIdx.x >> 4;
    const int i0 = blockIdx.y * 64, j0 = blockIdx.x * 64;
    const int lr = threadIdx.x >> 2;
    const int lc = (threadIdx.x & 3) * 4;
    const int kr = threadIdx.x >> 4;
    const int jc = (threadIdx.x & 15) * 4;
    float acc[4][4] = {};
    for (int k0 = 0; k0 < 512; k0 += 16) {
        const float4 av = *reinterpret_cast<const float4*>(
            p1w + (size_t)(i0 + lr) * 1024 + 512 + k0 + lc);
        As[lc + 0][lr] = av.x; As[lc + 1][lr] = av.y;
        As[lc + 2][lr] = av.z; As[lc + 3][lr] = av.w;
        const float4 bv = *reinterpret_cast<const float4*>(
            outw + (size_t)(k0 + kr) * 512 + j0 + jc);
        Bs[kr][jc + 0] = bv.x; Bs[kr][jc + 1] = bv.y;
        Bs[kr][jc + 2] = bv.z; Bs[kr][jc + 3] = bv.w;
        __syncthreads();
        #pragma unroll
        for (int kk = 0; kk < 16; ++kk) {
            float a[4], b[4];
            #pragma unroll
            for (int i = 0; i < 4; ++i) a[i] = As[kk][ty * 4 + i];
            #pragma unroll
            for (int jj = 0; jj < 4; ++jj) b[jj] = Bs[kk][tx * 4 + jj];
            #pragma unroll
            for (int i = 0; i < 4; ++i)
                #pragma unroll
                for (int jj = 0; jj < 4; ++jj)
                    acc[i][jj] = fmaf(a[i], b[jj], acc[i][jj]);
        }
        __syncthreads();
    }
    #pragma unroll
    for (int i = 0; i < 4; ++i)
        #pragma unroll
        for (int jj = 0; jj < 4; ++jj)
            p1cb[(size_t)(i0 + ty * 4 + i) * 1024 + 512 + j0 + tx * 4 + jj] =
                f2bf(acc[i][jj]);
}

// bias2[i] = p1_b[i] + sum_k p1_w[i][512+k] * out_b[k]
__global__ __launch_bounds__(64) void fold_bias(
    const float* __restrict__ p1w, const float* __restrict__ outb,
    const float* __restrict__ p1b, float* __restrict__ bias2)
{
    const int i = blockIdx.x, lane = threadIdx.x;
    float s = 0.0f;
    #pragma unroll
    for (int k = lane; k < 512; k += 64)
        s += p1w[(size_t)i * 1024 + 512 + k] * outb[k];
    #pragma unroll
    for (int off = 32; off > 0; off >>= 1) s += __shfl_down(s, off);
    if (lane == 0) bias2[i] = s + p1b[i];
}

// ---------------- bf16 MFMA GEMM: C[M,N] = A[M,K] @ W[N,K]^T (+bias) --------
// m97 structure: 128x128 tile, BK=32, 4 waves, global_load_lds width-16 for W.
// XCD-chunked bijective blockIdx swizzle (T1): each XCD owns contiguous
// complete row-panels -> A-panel fetched by exactly one XCD L2.
// A_MODE: 0 = bf16 via global_load_lds
//         1 = fp32 source, reg-staged convert to bf16 (in-flight cvt)
//         2 = two bf16 sources split at column K1 (concat along K)
// STATS: emit per-64-col partial row (sum,sumsq) into stats[row][8] float2
// (requires N==512, grid.x==4).
template<int A_MODE, bool STATS>
__global__ __launch_bounds__(256) void gemm_bf16(
    const void* __restrict__ A1v, const void* __restrict__ A2v, int K1, int K,
    const u16* __restrict__ W, const float* __restrict__ bias,
    u16* __restrict__ C, int N, float* __restrict__ stats)
{
    __shared__ __bf16 As[128 * 32];
    __shared__ __bf16 Ws[128 * 32];
    const int tid = threadIdx.x;
    const int w = tid >> 6, lane = tid & 63;

    // T1 swizzle: nwg divisible by 8 by construction
    const u32 nx = gridDim.x;
    const u32 orig = blockIdx.y * nx + blockIdx.x;
    const u32 nwg = nx * gridDim.y;
    const u32 wgid = (orig & 7u) * (nwg >> 3) + (orig >> 3);
    const int bx = wgid % nx;
    const int row0 = (int)(wgid / nx) * 128;
    const int col0 = bx * 128;

    const int wr = (w >> 1) * 64, wc = (w & 1) * 64;
    const int fr = lane & 15, fg = lane >> 4;

    // bf16 A / W staging geometry (global_load_lds)
    int srow[2], scol[2], soff[2];
    #pragma unroll
    for (int c = 0; c < 2; ++c) {
        const int bo = w * 2048 + c * 1024 + lane * 16;
        srow[c] = bo >> 6;
        scol[c] = (bo & 63) >> 1;
        soff[c] = (w * 2048 + c * 1024) >> 1;
    }
    // fp32 A staging geometry (reg-staged): thread -> row ar, 16 cols at ac
    const int ar = tid >> 1;
    const int ac = (tid & 1) * 16;

    f32x4 acc[4][4] = {};

    for (int k0 = 0; k0 < K; k0 += 32) {
        if (A_MODE == 1) {
            const float* Af = (const float*)A1v;
            const float* src = Af + (size_t)(row0 + ar) * K + k0 + ac;
            const float4 v0 = *reinterpret_cast<const float4*>(src);
            const float4 v1 = *reinterpret_cast<const float4*>(src + 4);
            const float4 v2 = *reinterpret_cast<const float4*>(src + 8);
            const float4 v3 = *reinterpret_cast<const float4*>(src + 12);
            u16x8 p0, p1;
            p0[0] = f2bf(v0.x); p0[1] = f2bf(v0.y); p0[2] = f2bf(v0.z); p0[3] = f2bf(v0.w);
            p0[4] = f2bf(v1.x); p0[5] = f2bf(v1.y); p0[6] = f2bf(v1.z); p0[7] = f2bf(v1.w);
            p1[0] = f2bf(v2.x); p1[1] = f2bf(v2.y); p1[2] = f2bf(v2.z); p1[3] = f2bf(v2.w);
            p1[4] = f2bf(v3.x); p1[5] = f2bf(v3.y); p1[6] = f2bf(v3.z); p1[7] = f2bf(v3.w);
            // trailing barrier of previous iter guarantees reads are done
            *reinterpret_cast<u16x8*>((u16*)As + ar * 32 + ac) = p0;
            *reinterpret_cast<u16x8*>((u16*)As + ar * 32 + ac + 8) = p1;
        } else {
            #pragma unroll
            for (int c = 0; c < 2; ++c) {
                const u16* asrc;
                if (A_MODE == 2) {
                    const bool first = (k0 < K1);
                    const u16* base = first ? (const u16*)A1v : (const u16*)A2v;
                    const int ldk = first ? K1 : (K - K1);
                    const int kk  = first ? k0 : (k0 - K1);
                    asrc = base + (size_t)(row0 + srow[c]) * ldk + kk + scol[c];
                } else {
                    asrc = (const u16*)A1v + (size_t)(row0 + srow[c]) * K + k0 + scol[c];
                }
                __builtin_amdgcn_global_load_lds(
                    (const __attribute__((address_space(1))) u32*)asrc,
                    (__attribute__((address_space(3))) u32*)(As + soff[c]), 16, 0, 0);
            }
        }
        #pragma unroll
        for (int c = 0; c < 2; ++c) {
            const u16* wsrc = W + (size_t)(col0 + srow[c]) * K + k0 + scol[c];
            __builtin_amdgcn_global_load_lds(
                (const __attribute__((address_space(1))) u32*)wsrc,
                (__attribute__((address_space(3))) u32*)(Ws + soff[c]), 16, 0, 0);
        }
        __syncthreads();

        bf16x8 af[4], bfr[4];
        #pragma unroll
        for (int m = 0; m < 4; ++m) {
            af[m]  = *(const bf16x8*)(As + (wr + m * 16 + fr) * 32 + fg * 8);
            bfr[m] = *(const bf16x8*)(Ws + (wc + m * 16 + fr) * 32 + fg * 8);
        }
        #pragma unroll
        for (int m = 0; m < 4; ++m)
            #pragma unroll
            for (int n = 0; n < 4; ++n)
                acc[m][n] = __builtin_amdgcn_mfma_f32_16x16x32_bf16(
                    af[m], bfr[n], acc[m][n], 0, 0, 0);
        __syncthreads();
    }

    // bias add (pre-stats, pre-round)
    if (bias) {
        #pragma unroll
        for (int n = 0; n < 4; ++n) {
            const float bv = bias[col0 + wc + n * 16 + fr];
            #pragma unroll
            for (int m = 0; m < 4; ++m)
                #pragma unroll
                for (int r = 0; r < 4; ++r)
                    acc[m][n][r] += bv;
        }
    }

    // C/D layout: col=lane&15, row=(lane>>4)*4+reg  [m89-verified]
    #pragma unroll
    for (int m = 0; m < 4; ++m)
        #pragma unroll
        for (int n = 0; n < 4; ++n) {
            const int col = col0 + wc + n * 16 + fr;
            #pragma unroll
            for (int r = 0; r < 4; ++r) {
                const int row = row0 + wr + m * 16 + fg * 4 + r;
                C[(size_t)row * N + col] = f2bf(acc[m][n][r]);
            }
        }

    if (STATS) {
        float ps[4][4], pq[4][4];
        #pragma unroll
        for (int m = 0; m < 4; ++m)
            #pragma unroll
            for (int r = 0; r < 4; ++r) {
                float s = 0.0f, q2 = 0.0f;
                #pragma unroll
                for (int n = 0; n < 4; ++n) {
                    const float v = acc[m][n][r];
                    s += v; q2 = fmaf(v, v, q2);
                }
                ps[m][r] = s; pq[m][r] = q2;
            }
        #pragma unroll
        for (int off = 1; off < 16; off <<= 1)
            #pragma unroll
            for (int m = 0; m < 4; ++m)
                #pragma unroll
                for (int r = 0; r < 4; ++r) {
                    ps[m][r] += __shfl_xor(ps[m][r], off);
                    pq[m][r] += __shfl_xor(pq[m][r], off);
                }
        if (fr == 0) {
            const int cb = bx * 2 + (w & 1);
            #pragma unroll
            for (int m = 0; m < 4; ++m)
                #pragma unroll
                for (int r = 0; r < 4; ++r) {
                    const int row = row0 + wr + m * 16 + fg * 4 + r;
                    *reinterpret_cast<float2*>(stats + ((size_t)row * 8 + cb) * 2) =
                        make_float2(ps[m][r], pq[m][r]);
                }
        }
    }
}

// ---------------- Row LayerNorm in-place (bf16 x + precomputed stats) -------
template<bool GELU>
__global__ __launch_bounds__(256) void ln_rows_s(
    u16* __restrict__ X, const float* __restrict__ stats,
    const float* __restrict__ g, const float* __restrict__ b)
{
    const size_t row = blockIdx.x;
    float s = 0.0f, q2 = 0.0f;
    #pragma unroll
    for (int cb = 0; cb < 8; ++cb) {
        s  += stats[(row * 8 + cb) * 2];
        q2 += stats[(row * 8 + cb) * 2 + 1];
    }
    const float mu = s * (1.0f / 512.0f);
    const float var = q2 * (1.0f / 512.0f) - mu * mu;
    const float rs = rsqrtf(var + 1e-5f);
    const int t = threadIdx.x;
    const ushort2 xv = *reinterpret_cast<const ushort2*>(X + row * 512 + 2 * t);
    const float2 gg = *reinterpret_cast<const float2*>(g + 2 * t);
    const float2 bb = *reinterpret_cast<const float2*>(b + 2 * t);
    float y0 = (bf2f(xv.x) - mu) * rs * gg.x + bb.x;
    float y1 = (bf2f(xv.y) - mu) * rs * gg.y + bb.y;
    if (GELU) { y0 = gelu_exact(y0); y1 = gelu_exact(y1); }
    *reinterpret_cast<ushort2*>(X + row * 512 + 2 * t) = make_ushort2(f2bf(y0), f2bf(y1));
}

// ---------------- Attention: persistent, wave per (line, head) ----------
__global__ __launch_bounds__(512) void attn_kernel(
    const u16* __restrict__ qh, const u16* __restrict__ kvb,
    const int* __restrict__ kidx, const int* __restrict__ ncnt,
    u16* __restrict__ ctx)
{
    const int head = threadIdx.x >> 6;
    const int lane = threadIdx.x & 63;
    const int mi = lane & 7, dg = lane >> 3;
    const bool b0 = (mi & 1), b1 = (mi & 2), b2 = (mi & 4);
    const int doff = (b0 ? 4 : 0) + (b1 ? 2 : 0) + (b2 ? 1 : 0);

    for (int l = blockIdx.x; l < 32768; l += gridDim.x) {
        const int cnt = ncnt[l];
        const int idx = kidx[l * 8 + mi];
        const size_t kvbase = (size_t)idx * 1024 + head * 64 + dg * 8;

        const u16x8 qv = *(const u16x8*)(qh + (size_t)l * 512 + head * 64 + dg * 8);
        const u16x8 kv = *(const u16x8*)(kvb + kvbase);
        const u16x8 vv = *(const u16x8*)(kvb + kvbase + 512);   // early V load

        float p = 0.0f;
        #pragma unroll
        for (int jj = 0; jj < 8; ++jj) p = fmaf(bf2f(qv[jj]), bf2f(kv[jj]), p);
        p += __shfl_xor(p, 8); p += __shfl_xor(p, 16); p += __shfl_xor(p, 32);

        float s = (mi < cnt) ? p * 0.125f : -3.402823466e38f;
        float mx = s;
        mx = fmaxf(mx, __shfl_xor(mx, 1));
        mx = fmaxf(mx, __shfl_xor(mx, 2));
        mx = fmaxf(mx, __shfl_xor(mx, 4));
        const float e = __expf(s - mx);
        float den = e;
        den += __shfl_xor(den, 1); den += __shfl_xor(den, 2); den += __shfl_xor(den, 4);
        const float wgt = e / den;

        float c[8];
        #pragma unroll
        for (int jj = 0; jj < 8; ++jj) c[jj] = wgt * bf2f(vv[jj]);

        #pragma unroll
        for (int jj = 0; jj < 4; ++jj) {
            const float snd = b0 ? c[jj] : c[jj + 4];
            const float rec = __shfl_xor(snd, 1);
            c[jj] = (b0 ? c[jj + 4] : c[jj]) + rec;
        }
        #pragma unroll
        for (int jj = 0; jj < 2; ++jj) {
            const float snd = b1 ? c[jj] : c[jj + 2];
            const float rec = __shfl_xor(snd, 2);
            c[jj] = (b1 ? c[jj + 2] : c[jj]) + rec;
        }
        {
            const float snd = b2 ? c[0] : c[1];
            const float rec = __shfl_xor(snd, 4);
            c[0] = (b2 ? c[1] : c[0]) + rec;
        }
        ctx[(size_t)l * 512 + head * 64 + dg * 8 + doff] = f2bf(c[0]);
    }
}

// ---------------- Final: h2 = h1 + gelu(LN(h2_raw)); sigmoid(head) ----------
__global__ __launch_bounds__(256) void final_head_s(
    const u16* __restrict__ h1, const u16* __restrict__ h2raw,
    const float* __restrict__ stats,
    const float* __restrict__ g, const float* __restrict__ b,
    const float* __restrict__ hw, const float* __restrict__ hb,
    float* __restrict__ out)
{
    __shared__ float sm[4];
    const size_t row = blockIdx.x;
    float s = 0.0f, q2 = 0.0f;
    #pragma unroll
    for (int cb = 0; cb < 8; ++cb) {
        s  += stats[(row * 8 + cb) * 2];
        q2 += stats[(row * 8 + cb) * 2 + 1];
    }
    const float mu = s * (1.0f / 512.0f);
    const float var = q2 * (1.0f / 512.0f) - mu * mu;
    const float rs = rsqrtf(var + 1e-5f);
    const int t = threadIdx.x;
    const ushort2 xv = *reinterpret_cast<const ushort2*>(h2raw + row * 512 + 2 * t);
    const ushort2 hv = *reinterpret_cast<const ushort2*>(h1 + row * 512 + 2 * t);
    const float2 gg = *reinterpret_cast<const float2*>(g + 2 * t);
    const float2 bb = *reinterpret_cast<const float2*>(b + 2 * t);
    const float2 hwv = *reinterpret_cast<const float2*>(hw + 2 * t);
    const float y0 = bf2f(hv.x) + gelu_exact((bf2f(xv.x) - mu) * rs * gg.x + bb.x);
    const float y1 = bf2f(hv.y) + gelu_exact((bf2f(xv.y) - mu) * rs * gg.y + bb.y);
    const float d = breduce1(y0 * hwv.x + y1 * hwv.y, sm);
    if (t == 0) out[row] = 1.0f / (1.0f + expf(-(d + hb[0])));
}

extern "C" void kernel_launch(void* const* d_in, const int* in_sizes, int n_in,
                              void* d_out, int out_size, void* d_ws, size_t ws_size,
                              hipStream_t stream)
{
    const float* lines  = (const float*)d_in[0];   // [32768,768]
    const float* blocks = (const float*)d_in[1];   // [8192,768]
    const float* Wq     = (const float*)d_in[2];   // [512,768]
    const float* Wkv    = (const float*)d_in[3];   // [512,768]
    const float* qn_g   = (const float*)d_in[4];
    const float* qn_b   = (const float*)d_in[5];
    const float* kvn_g  = (const float*)d_in[6];
    const float* kvn_b  = (const float*)d_in[7];
    const float* in_w   = (const float*)d_in[8];   // [1536,512]
    const float* in_b   = (const float*)d_in[9];   // [1536]
    const float* out_w  = (const float*)d_in[10];  // [512,512]
    const float* out_b  = (const float*)d_in[11];
    const float* p1_w   = (const float*)d_in[12];  // [512,1024]
    const float* p1_b   = (const float*)d_in[13];
    const float* ln1_g  = (const float*)d_in[14];
    const float* ln1_b  = (const float*)d_in[15];
    const float* p2_w   = (const float*)d_in[16];  // [512,512]
    const float* p2_b   = (const float*)d_in[17];
    const float* ln2_g  = (const float*)d_in[18];
    const float* ln2_b  = (const float*)d_in[19];
    const float* head_w = (const float*)d_in[20];  // [1,512]
    const float* head_b = (const float*)d_in[21];  // [1]
    const int*   kidx   = (const int*)d_in[22];    // [32768,8]
    const int*   ncnt   = (const int*)d_in[23];    // [32768]
    float* out = (float*)d_out;                    // [32768]

    // workspace layout:
    //  0M   qb    [32768,512] bf16   q_raw -> q
    //  32M  qhb   [32768,512] bf16   qh -> h1_raw -> h1
    //  64M  ctxb  [32768,512] bf16   ctx -> h2_raw
    //  96M  kvbb  [8192,1024] bf16
    //  112M bkvb  [8192,512]  bf16   bkv_raw -> bkv
    //  120M stats_q(2M); 124M stats_h1(2M); 128M stats_h2(2M); 132M stats_bkv
    //  136M weights (~4.5M); bias2 after
    char* wsb = (char*)d_ws;
    u16* qb    = (u16*)(wsb);
    u16* qhb   = (u16*)(wsb + (32ull << 20));
    u16* ctxb  = (u16*)(wsb + (64ull << 20));
    u16* kvbb  = (u16*)(wsb + (96ull << 20));
    u16* bkvb  = (u16*)(wsb + (112ull << 20));
    float* stats_q   = (float*)(wsb + (120ull << 20));
    float* stats_h1  = (float*)(wsb + (124ull << 20));
    float* stats_h2  = (float*)(wsb + (128ull << 20));
    float* stats_bkv = (float*)(wsb + (132ull << 20));
    u16* Wqb   = (u16*)(wsb + (136ull << 20));
    u16* Wkvb  = Wqb + 512 * 768;
    u16* inwb  = Wkvb + 512 * 768;
    u16* p1cb  = inwb + 1536 * 512;                // [512][1024] combined p1a|W2
    u16* p2wb  = p1cb + 512 * 1024;
    float* bias2f = (float*)(p2wb + 512 * 512);

    // weights: one fused conversion launch (p1 cols 512.. overwritten by fold_w2)
    {
        CvtJobs j;
        const float* ss[5] = { Wq, Wkv, in_w, p1_w, p2_w };
        u16* dd[5] = { Wqb, Wkvb, inwb, p1cb, p2wb };
        const int nn[5] = { 512 * 768, 512 * 768, 1536 * 512, 512 * 1024, 512 * 512 };
        int c = 0;
        for (int k = 0; k < 5; ++k) { j.s[k] = ss[k]; j.d[k] = dd[k]; j.cum[k] = c; c += nn[k] / 4; }
        j.cum[5] = c;
        cvt_multi<<<(c + 255) / 256, 256, 0, stream>>>(j);
    }
    // fold out-proj into p1
    fold_w2<<<dim3(8, 8), 256, 0, stream>>>(p1_w, out_w, p1cb);
    fold_bias<<<512, 64, 0, stream>>>(p1_w, out_b, p1_b, bias2f);

    // 1. bkv_raw = blocks @ Wkv^T  (fp32 A direct, bf16 + stats)  [8192,512]
    gemm_bf16<1, true><<<dim3(4, 64), 256, 0, stream>>>(
        blocks, nullptr, 768, 768, Wkvb, nullptr, bkvb, 512, stats_bkv);
    // 2. bkv = LN(bkv_raw) in-place
    ln_rows_s<false><<<8192, 256, 0, stream>>>(bkvb, stats_bkv, kvn_g, kvn_b);
    // 3. kvbb = bkv @ [wk;wv]^T + [bk;bv]                         [8192,1024]
    gemm_bf16<0, false><<<dim3(8, 64), 256, 0, stream>>>(
        bkvb, nullptr, 512, 512, inwb + 512 * 512, in_b + 512, kvbb, 1024, nullptr);
    // 4. q_raw = lines @ Wq^T  (fp32 A direct, bf16 + stats)      [32768,512]
    gemm_bf16<1, true><<<dim3(4, 256), 256, 0, stream>>>(
        lines, nullptr, 768, 768, Wqb, nullptr, qb, 512, stats_q);
    // 5. q = LN(q_raw) in-place
    ln_rows_s<false><<<32768, 256, 0, stream>>>(qb, stats_q, qn_g, qn_b);
    // 6. qh = q @ wq_i^T + bq_i                                   [32768,512]
    gemm_bf16<0, false><<<dim3(4, 256), 256, 0, stream>>>(
        qb, nullptr, 512, 512, inwb, in_b, qhb, 512, nullptr);
    // 7. ctx (attention, persistent grid)
    attn_kernel<<<2048, 512, 0, stream>>>(qhb, kvbb, kidx, ncnt, ctxb);
    // 8. h1_raw = q@p1a^T + ctx@W2^T + bias2  (into qhb; qh dead) + stats
    gemm_bf16<2, true><<<dim3(4, 256), 256, 0, stream>>>(
        qb, ctxb, 512, 1024, p1cb, bias2f, qhb, 512, stats_h1);
    // 9. h1 = gelu(LN(h1_raw)) in-place
    ln_rows_s<true><<<32768, 256, 0, stream>>>(qhb, stats_h1, ln1_g, ln1_b);
    // 10. h2_raw = h1 @ p2_w^T + p2_b  (into ctxb; ctx dead) + stats
    gemm_bf16<0, true><<<dim3(4, 256), 256, 0, stream>>>(
        qhb, nullptr, 512, 512, p2wb, p2_b, ctxb, 512, stats_h2);
    // 11. out = sigmoid((h1 + gelu(LN(h2_raw))) . head_w + head_b)
    final_head_s<<<32768, 256, 0, stream>>>(qhb, ctxb, stats_h2, ln2_g, ln2_b,
                                            head_w, head_b, out);
}

// Round 8
// 449.545 us; speedup vs baseline: 1.4231x; 1.0392x over previous
//
#include <hip/hip_runtime.h>
#include <math.h>

// L=32768 lines, M=8 neighbors, B=8192 blocks, LIN=BIN=768, H=512, NH=8, DH=64

typedef unsigned short u16;
typedef unsigned int u32;
using bf16x8 = __attribute__((ext_vector_type(8))) __bf16;
using u16x8  = __attribute__((ext_vector_type(8))) u16;
using f32x4  = __attribute__((ext_vector_type(4))) float;

__device__ __forceinline__ u16 f2bf(float f) {
    u32 u = __builtin_bit_cast(u32, f);
    u32 r = u + 0x7fffu + ((u >> 16) & 1u);
    return (u16)(r >> 16);
}
__device__ __forceinline__ float bf2f(u16 h) {
    return __builtin_bit_cast(float, (u32)h << 16);
}
__device__ __forceinline__ float gelu_exact(float x) {
    return 0.5f * x * (1.0f + erff(x * 0.70710678118654752440f));
}

// Block-wide reduction of one value across 256 threads (4 waves).
__device__ __forceinline__ float breduce1(float s0, float* sm) {
    #pragma unroll
    for (int off = 32; off > 0; off >>= 1) s0 += __shfl_down(s0, off);
    const int lane = threadIdx.x & 63, w = threadIdx.x >> 6;
    __syncthreads();
    if (lane == 0) sm[w] = s0;
    __syncthreads();
    return sm[0] + sm[1] + sm[2] + sm[3];
}

// ---------------- fused multi-array conversion (weights) ----------------
struct CvtJobs {
    const float* s[5];
    u16* d[5];
    int cum[6];   // cumulative quad counts
};
__global__ __launch_bounds__(256) void cvt_multi(CvtJobs j)
{
    const int g = blockIdx.x * 256 + threadIdx.x;   // quad index
    if (g >= j.cum[5]) return;
    int seg = 0;
    #pragma unroll
    for (int k = 1; k < 5; ++k) seg += (g >= j.cum[k]);
    const int q = g - j.cum[seg];
    const float4 v = *reinterpret_cast<const float4*>(j.s[seg] + q * 4);
    ushort4 o = make_ushort4(f2bf(v.x), f2bf(v.y), f2bf(v.z), f2bf(v.w));
    *reinterpret_cast<ushort4*>(j.d[seg] + q * 4) = o;
}

// ---------------- W2 fold: W2 = p1b @ out_w  (fp32 in, bf16 out) ------------
__global__ __launch_bounds__(256) void fold_w2(
    const float* __restrict__ p1w, const float* __restrict__ outw,
    u16* __restrict__ p1cb)
{
    __shared__ float As[16][65];   // [k][i]
    __shared__ float Bs[16][65];   // [k][j]
    const int tx = threadIdx.x & 15, ty = threadIdx.x >> 4;
    const int i0 = blockIdx.y * 64, j0 = blockIdx.x * 64;
    const int lr = threadIdx.x >> 2;
    const int lc = (threadIdx.x & 3) * 4;
    const int kr = threadIdx.x >> 4;
    const int jc = (threadIdx.x & 15) * 4;
    float acc[4][4] = {};
    for (int k0 = 0; k0 < 512; k0 += 16) {
        const float4 av = *reinterpret_cast<const float4*>(
            p1w + (size_t)(i0 + lr) * 1024 + 512 + k0 + lc);
        As[lc + 0][lr] = av.x; As[lc + 1][lr] = av.y;
        As[lc + 2][lr] = av.z; As[lc + 3][lr] = av.w;
        const float4 bv = *reinterpret_cast<const float4*>(
            outw + (size_t)(k0 + kr) * 512 + j0 + jc);
        Bs[kr][jc + 0] = bv.x; Bs[kr][jc + 1] = bv.y;
        Bs[kr][jc + 2] = bv.z; Bs[kr][jc + 3] = bv.w;
        __syncthreads();
        #pragma unroll
        for (int kk = 0; kk < 16; ++kk) {
            float a[4], b[4];
            #pragma unroll
            for (int i = 0; i < 4; ++i) a[i] = As[kk][ty * 4 + i];
            #pragma unroll
            for (int jj = 0; jj < 4; ++jj) b[jj] = Bs[kk][tx * 4 + jj];
            #pragma unroll
            for (int i = 0; i < 4; ++i)
                #pragma unroll
                for (int jj = 0; jj < 4; ++jj)
                    acc[i][jj] = fmaf(a[i], b[jj], acc[i][jj]);
        }
        __syncthreads();
    }
    #pragma unroll
    for (int i = 0; i < 4; ++i)
        #pragma unroll
        for (int jj = 0; jj < 4; ++jj)
            p1cb[(size_t)(i0 + ty * 4 + i) * 1024 + 512 + j0 + tx * 4 + jj] =
                f2bf(acc[i][jj]);
}

// bias2[i] = p1_b[i] + sum_k p1_w[i][512+k] * out_b[k]
__global__ __launch_bounds__(64) void fold_bias(
    const float* __restrict__ p1w, const float* __restrict__ outb,
    const float* __restrict__ p1b, float* __restrict__ bias2)
{
    const int i = blockIdx.x, lane = threadIdx.x;
    float s = 0.0f;
    #pragma unroll
    for (int k = lane; k < 512; k += 64)
        s += p1w[(size_t)i * 1024 + 512 + k] * outb[k];
    #pragma unroll
    for (int off = 32; off > 0; off >>= 1) s += __shfl_down(s, off);
    if (lane == 0) bias2[i] = s + p1b[i];
}

// ---------------- bf16 MFMA GEMM: C[M,N] = A[M,K] @ W[N,K]^T (+bias) --------
// 128x128 tile, BK=32, 4 waves, 2-phase double-buffered pipeline:
// per K-step: STAGE(next tile -> buf^1) || ds_read+MFMA(buf) ; one barrier.
// XCD-chunked bijective blockIdx swizzle (T1).
// A_MODE: 0 = bf16 via global_load_lds
//         1 = fp32 source, reg-staged convert to bf16 (write-late after MFMA)
//         2 = two bf16 sources split at column K1 (concat along K)
// STATS: emit per-64-col partial row (sum,sumsq) into stats[row][8] float2
// (requires N==512, grid.x==4).
template<int A_MODE, bool STATS>
__global__ __launch_bounds__(256) void gemm_bf16(
    const void* __restrict__ A1v, const void* __restrict__ A2v, int K1, int K,
    const u16* __restrict__ W, const float* __restrict__ bias,
    u16* __restrict__ C, int N, float* __restrict__ stats)
{
    __shared__ __bf16 As[2 * 128 * 32];
    __shared__ __bf16 Ws[2 * 128 * 32];
    const int tid = threadIdx.x;
    const int w = tid >> 6, lane = tid & 63;

    // T1 swizzle: nwg divisible by 8 by construction
    const u32 nx = gridDim.x;
    const u32 orig = blockIdx.y * nx + blockIdx.x;
    const u32 nwg = nx * gridDim.y;
    const u32 wgid = (orig & 7u) * (nwg >> 3) + (orig >> 3);
    const int bx = wgid % nx;
    const int row0 = (int)(wgid / nx) * 128;
    const int col0 = bx * 128;

    const int wr = (w >> 1) * 64, wc = (w & 1) * 64;
    const int fr = lane & 15, fg = lane >> 4;

    // gload_lds staging geometry (bf16 A and W)
    int srow[2], scol[2], soff[2];
    #pragma unroll
    for (int c = 0; c < 2; ++c) {
        const int bo = w * 2048 + c * 1024 + lane * 16;
        srow[c] = bo >> 6;
        scol[c] = (bo & 63) >> 1;
        soff[c] = (w * 2048 + c * 1024) >> 1;
    }
    // fp32 A staging geometry (reg-staged): thread -> row ar, 16 cols at ac
    const int ar = tid >> 1;
    const int ac = (tid & 1) * 16;

    f32x4 acc[4][4] = {};
    float4 av0, av1, av2, av3;   // A_MODE==1 in-flight regs

    auto stage_issue = [&](int k0, int buf) {
        if (A_MODE == 1) {
            const float* src = (const float*)A1v + (size_t)(row0 + ar) * K + k0 + ac;
            av0 = *reinterpret_cast<const float4*>(src);
            av1 = *reinterpret_cast<const float4*>(src + 4);
            av2 = *reinterpret_cast<const float4*>(src + 8);
            av3 = *reinterpret_cast<const float4*>(src + 12);
        } else {
            #pragma unroll
            for (int c = 0; c < 2; ++c) {
                const u16* asrc;
                if (A_MODE == 2) {
                    const bool first = (k0 < K1);
                    const u16* base = first ? (const u16*)A1v : (const u16*)A2v;
                    const int ldk = first ? K1 : (K - K1);
                    const int kk  = first ? k0 : (k0 - K1);
                    asrc = base + (size_t)(row0 + srow[c]) * ldk + kk + scol[c];
                } else {
                    asrc = (const u16*)A1v + (size_t)(row0 + srow[c]) * K + k0 + scol[c];
                }
                __builtin_amdgcn_global_load_lds(
                    (const __attribute__((address_space(1))) u32*)asrc,
                    (__attribute__((address_space(3))) u32*)(As + buf * 4096 + soff[c]),
                    16, 0, 0);
            }
        }
        #pragma unroll
        for (int c = 0; c < 2; ++c) {
            const u16* wsrc = W + (size_t)(col0 + srow[c]) * K + k0 + scol[c];
            __builtin_amdgcn_global_load_lds(
                (const __attribute__((address_space(1))) u32*)wsrc,
                (__attribute__((address_space(3))) u32*)(Ws + buf * 4096 + soff[c]),
                16, 0, 0);
        }
    };
    auto stage_write_a = [&](int buf) {   // A_MODE==1 only: cvt + ds_write
        u16x8 p0, p1;
        p0[0] = f2bf(av0.x); p0[1] = f2bf(av0.y); p0[2] = f2bf(av0.z); p0[3] = f2bf(av0.w);
        p0[4] = f2bf(av1.x); p0[5] = f2bf(av1.y); p0[6] = f2bf(av1.z); p0[7] = f2bf(av1.w);
        p1[0] = f2bf(av2.x); p1[1] = f2bf(av2.y); p1[2] = f2bf(av2.z); p1[3] = f2bf(av2.w);
        p1[4] = f2bf(av3.x); p1[5] = f2bf(av3.y); p1[6] = f2bf(av3.z); p1[7] = f2bf(av3.w);
        *reinterpret_cast<u16x8*>((u16*)As + buf * 4096 + ar * 32 + ac) = p0;
        *reinterpret_cast<u16x8*>((u16*)As + buf * 4096 + ar * 32 + ac + 8) = p1;
    };

    const int NT = K >> 5;
    int cur = 0;

    // prologue: stage tile 0 into buf 0
    stage_issue(0, 0);
    if (A_MODE == 1) stage_write_a(0);   // compiler inserts vmcnt wait for av regs
    __syncthreads();                     // drains vmcnt+lgkm; tile 0 ready

    for (int t = 0; t < NT; ++t) {
        const bool have_next = (t + 1 < NT);
        if (have_next) stage_issue((t + 1) << 5, cur ^ 1);

        bf16x8 af[4], bfr[4];
        #pragma unroll
        for (int m = 0; m < 4; ++m) {
            af[m]  = *(const bf16x8*)(As + cur * 4096 + (wr + m * 16 + fr) * 32 + fg * 8);
            bfr[m] = *(const bf16x8*)(Ws + cur * 4096 + (wc + m * 16 + fr) * 32 + fg * 8);
        }
        #pragma unroll
        for (int m = 0; m < 4; ++m)
            #pragma unroll
            for (int n = 0; n < 4; ++n)
                acc[m][n] = __builtin_amdgcn_mfma_f32_16x16x32_bf16(
                    af[m], bfr[n], acc[m][n], 0, 0, 0);

        if (have_next && A_MODE == 1) stage_write_a(cur ^ 1);
        __syncthreads();                 // next tile fully staged
        cur ^= 1;
    }

    // bias add (pre-stats, pre-round)
    if (bias) {
        #pragma unroll
        for (int n = 0; n < 4; ++n) {
            const float bv = bias[col0 + wc + n * 16 + fr];
            #pragma unroll
            for (int m = 0; m < 4; ++m)
                #pragma unroll
                for (int r = 0; r < 4; ++r)
                    acc[m][n][r] += bv;
        }
    }

    // C/D layout: col=lane&15, row=(lane>>4)*4+reg  [m89-verified]
    #pragma unroll
    for (int m = 0; m < 4; ++m)
        #pragma unroll
        for (int n = 0; n < 4; ++n) {
            const int col = col0 + wc + n * 16 + fr;
            #pragma unroll
            for (int r = 0; r < 4; ++r) {
                const int row = row0 + wr + m * 16 + fg * 4 + r;
                C[(size_t)row * N + col] = f2bf(acc[m][n][r]);
            }
        }

    if (STATS) {
        float ps[4][4], pq[4][4];
        #pragma unroll
        for (int m = 0; m < 4; ++m)
            #pragma unroll
            for (int r = 0; r < 4; ++r) {
                float s = 0.0f, q2 = 0.0f;
                #pragma unroll
                for (int n = 0; n < 4; ++n) {
                    const float v = acc[m][n][r];
                    s += v; q2 = fmaf(v, v, q2);
                }
                ps[m][r] = s; pq[m][r] = q2;
            }
        #pragma unroll
        for (int off = 1; off < 16; off <<= 1)
            #pragma unroll
            for (int m = 0; m < 4; ++m)
                #pragma unroll
                for (int r = 0; r < 4; ++r) {
                    ps[m][r] += __shfl_xor(ps[m][r], off);
                    pq[m][r] += __shfl_xor(pq[m][r], off);
                }
        if (fr == 0) {
            const int cb = bx * 2 + (w & 1);
            #pragma unroll
            for (int m = 0; m < 4; ++m)
                #pragma unroll
                for (int r = 0; r < 4; ++r) {
                    const int row = row0 + wr + m * 16 + fg * 4 + r;
                    *reinterpret_cast<float2*>(stats + ((size_t)row * 8 + cb) * 2) =
                        make_float2(ps[m][r], pq[m][r]);
                }
        }
    }
}

// ---------------- Row LayerNorm in-place (bf16 x + precomputed stats) -------
template<bool GELU>
__global__ __launch_bounds__(256) void ln_rows_s(
    u16* __restrict__ X, const float* __restrict__ stats,
    const float* __restrict__ g, const float* __restrict__ b)
{
    const size_t row = blockIdx.x;
    float s = 0.0f, q2 = 0.0f;
    #pragma unroll
    for (int cb = 0; cb < 8; ++cb) {
        s  += stats[(row * 8 + cb) * 2];
        q2 += stats[(row * 8 + cb) * 2 + 1];
    }
    const float mu = s * (1.0f / 512.0f);
    const float var = q2 * (1.0f / 512.0f) - mu * mu;
    const float rs = rsqrtf(var + 1e-5f);
    const int t = threadIdx.x;
    const ushort2 xv = *reinterpret_cast<const ushort2*>(X + row * 512 + 2 * t);
    const float2 gg = *reinterpret_cast<const float2*>(g + 2 * t);
    const float2 bb = *reinterpret_cast<const float2*>(b + 2 * t);
    float y0 = (bf2f(xv.x) - mu) * rs * gg.x + bb.x;
    float y1 = (bf2f(xv.y) - mu) * rs * gg.y + bb.y;
    if (GELU) { y0 = gelu_exact(y0); y1 = gelu_exact(y1); }
    *reinterpret_cast<ushort2*>(X + row * 512 + 2 * t) = make_ushort2(f2bf(y0), f2bf(y1));
}

// ---------------- Attention: persistent, wave per (line, head) ----------
__global__ __launch_bounds__(512) void attn_kernel(
    const u16* __restrict__ qh, const u16* __restrict__ kvb,
    const int* __restrict__ kidx, const int* __restrict__ ncnt,
    u16* __restrict__ ctx)
{
    const int head = threadIdx.x >> 6;
    const int lane = threadIdx.x & 63;
    const int mi = lane & 7, dg = lane >> 3;
    const bool b0 = (mi & 1), b1 = (mi & 2), b2 = (mi & 4);
    const int doff = (b0 ? 4 : 0) + (b1 ? 2 : 0) + (b2 ? 1 : 0);

    for (int l = blockIdx.x; l < 32768; l += gridDim.x) {
        const int cnt = ncnt[l];
        const int idx = kidx[l * 8 + mi];
        const size_t kvbase = (size_t)idx * 1024 + head * 64 + dg * 8;

        const u16x8 qv = *(const u16x8*)(qh + (size_t)l * 512 + head * 64 + dg * 8);
        const u16x8 kv = *(const u16x8*)(kvb + kvbase);
        const u16x8 vv = *(const u16x8*)(kvb + kvbase + 512);   // early V load

        float p = 0.0f;
        #pragma unroll
        for (int jj = 0; jj < 8; ++jj) p = fmaf(bf2f(qv[jj]), bf2f(kv[jj]), p);
        p += __shfl_xor(p, 8); p += __shfl_xor(p, 16); p += __shfl_xor(p, 32);

        float s = (mi < cnt) ? p * 0.125f : -3.402823466e38f;
        float mx = s;
        mx = fmaxf(mx, __shfl_xor(mx, 1));
        mx = fmaxf(mx, __shfl_xor(mx, 2));
        mx = fmaxf(mx, __shfl_xor(mx, 4));
        const float e = __expf(s - mx);
        float den = e;
        den += __shfl_xor(den, 1); den += __shfl_xor(den, 2); den += __shfl_xor(den, 4);
        const float wgt = e / den;

        float c[8];
        #pragma unroll
        for (int jj = 0; jj < 8; ++jj) c[jj] = wgt * bf2f(vv[jj]);

        #pragma unroll
        for (int jj = 0; jj < 4; ++jj) {
            const float snd = b0 ? c[jj] : c[jj + 4];
            const float rec = __shfl_xor(snd, 1);
            c[jj] = (b0 ? c[jj + 4] : c[jj]) + rec;
        }
        #pragma unroll
        for (int jj = 0; jj < 2; ++jj) {
            const float snd = b1 ? c[jj] : c[jj + 2];
            const float rec = __shfl_xor(snd, 2);
            c[jj] = (b1 ? c[jj + 2] : c[jj]) + rec;
        }
        {
            const float snd = b2 ? c[0] : c[1];
            const float rec = __shfl_xor(snd, 4);
            c[0] = (b2 ? c[1] : c[0]) + rec;
        }
        ctx[(size_t)l * 512 + head * 64 + dg * 8 + doff] = f2bf(c[0]);
    }
}

// ---------------- Final: h2 = h1 + gelu(LN(h2_raw)); sigmoid(head) ----------
__global__ __launch_bounds__(256) void final_head_s(
    const u16* __restrict__ h1, const u16* __restrict__ h2raw,
    const float* __restrict__ stats,
    const float* __restrict__ g, const float* __restrict__ b,
    const float* __restrict__ hw, const float* __restrict__ hb,
    float* __restrict__ out)
{
    __shared__ float sm[4];
    const size_t row = blockIdx.x;
    float s = 0.0f, q2 = 0.0f;
    #pragma unroll
    for (int cb = 0; cb < 8; ++cb) {
        s  += stats[(row * 8 + cb) * 2];
        q2 += stats[(row * 8 + cb) * 2 + 1];
    }
    const float mu = s * (1.0f / 512.0f);
    const float var = q2 * (1.0f / 512.0f) - mu * mu;
    const float rs = rsqrtf(var + 1e-5f);
    const int t = threadIdx.x;
    const ushort2 xv = *reinterpret_cast<const ushort2*>(h2raw + row * 512 + 2 * t);
    const ushort2 hv = *reinterpret_cast<const ushort2*>(h1 + row * 512 + 2 * t);
    const float2 gg = *reinterpret_cast<const float2*>(g + 2 * t);
    const float2 bb = *reinterpret_cast<const float2*>(b + 2 * t);
    const float2 hwv = *reinterpret_cast<const float2*>(hw + 2 * t);
    const float y0 = bf2f(hv.x) + gelu_exact((bf2f(xv.x) - mu) * rs * gg.x + bb.x);
    const float y1 = bf2f(hv.y) + gelu_exact((bf2f(xv.y) - mu) * rs * gg.y + bb.y);
    const float d = breduce1(y0 * hwv.x + y1 * hwv.y, sm);
    if (t == 0) out[row] = 1.0f / (1.0f + expf(-(d + hb[0])));
}

extern "C" void kernel_launch(void* const* d_in, const int* in_sizes, int n_in,
                              void* d_out, int out_size, void* d_ws, size_t ws_size,
                              hipStream_t stream)
{
    const float* lines  = (const float*)d_in[0];   // [32768,768]
    const float* blocks = (const float*)d_in[1];   // [8192,768]
    const float* Wq     = (const float*)d_in[2];   // [512,768]
    const float* Wkv    = (const float*)d_in[3];   // [512,768]
    const float* qn_g   = (const float*)d_in[4];
    const float* qn_b   = (const float*)d_in[5];
    const float* kvn_g  = (const float*)d_in[6];
    const float* kvn_b  = (const float*)d_in[7];
    const float* in_w   = (const float*)d_in[8];   // [1536,512]
    const float* in_b   = (const float*)d_in[9];   // [1536]
    const float* out_w  = (const float*)d_in[10];  // [512,512]
    const float* out_b  = (const float*)d_in[11];
    const float* p1_w   = (const float*)d_in[12];  // [512,1024]
    const float* p1_b   = (const float*)d_in[13];
    const float* ln1_g  = (const float*)d_in[14];
    const float* ln1_b  = (const float*)d_in[15];
    const float* p2_w   = (const float*)d_in[16];  // [512,512]
    const float* p2_b   = (const float*)d_in[17];
    const float* ln2_g  = (const float*)d_in[18];
    const float* ln2_b  = (const float*)d_in[19];
    const float* head_w = (const float*)d_in[20];  // [1,512]
    const float* head_b = (const float*)d_in[21];  // [1]
    const int*   kidx   = (const int*)d_in[22];    // [32768,8]
    const int*   ncnt   = (const int*)d_in[23];    // [32768]
    float* out = (float*)d_out;                    // [32768]

    // workspace layout:
    //  0M   qb    [32768,512] bf16   q_raw -> q
    //  32M  qhb   [32768,512] bf16   qh -> h1_raw -> h1
    //  64M  ctxb  [32768,512] bf16   ctx -> h2_raw
    //  96M  kvbb  [8192,1024] bf16
    //  112M bkvb  [8192,512]  bf16   bkv_raw -> bkv
    //  120M stats_q(2M); 124M stats_h1(2M); 128M stats_h2(2M); 132M stats_bkv
    //  136M weights (~4.5M); bias2 after
    char* wsb = (char*)d_ws;
    u16* qb    = (u16*)(wsb);
    u16* qhb   = (u16*)(wsb + (32ull << 20));
    u16* ctxb  = (u16*)(wsb + (64ull << 20));
    u16* kvbb  = (u16*)(wsb + (96ull << 20));
    u16* bkvb  = (u16*)(wsb + (112ull << 20));
    float* stats_q   = (float*)(wsb + (120ull << 20));
    float* stats_h1  = (float*)(wsb + (124ull << 20));
    float* stats_h2  = (float*)(wsb + (128ull << 20));
    float* stats_bkv = (float*)(wsb + (132ull << 20));
    u16* Wqb   = (u16*)(wsb + (136ull << 20));
    u16* Wkvb  = Wqb + 512 * 768;
    u16* inwb  = Wkvb + 512 * 768;
    u16* p1cb  = inwb + 1536 * 512;                // [512][1024] combined p1a|W2
    u16* p2wb  = p1cb + 512 * 1024;
    float* bias2f = (float*)(p2wb + 512 * 512);

    // weights: one fused conversion launch (p1 cols 512.. overwritten by fold_w2)
    {
        CvtJobs j;
        const float* ss[5] = { Wq, Wkv, in_w, p1_w, p2_w };
        u16* dd[5] = { Wqb, Wkvb, inwb, p1cb, p2wb };
        const int nn[5] = { 512 * 768, 512 * 768, 1536 * 512, 512 * 1024, 512 * 512 };
        int c = 0;
        for (int k = 0; k < 5; ++k) { j.s[k] = ss[k]; j.d[k] = dd[k]; j.cum[k] = c; c += nn[k] / 4; }
        j.cum[5] = c;
        cvt_multi<<<(c + 255) / 256, 256, 0, stream>>>(j);
    }
    // fold out-proj into p1
    fold_w2<<<dim3(8, 8), 256, 0, stream>>>(p1_w, out_w, p1cb);
    fold_bias<<<512, 64, 0, stream>>>(p1_w, out_b, p1_b, bias2f);

    // 1. bkv_raw = blocks @ Wkv^T  (fp32 A direct, bf16 + stats)  [8192,512]
    gemm_bf16<1, true><<<dim3(4, 64), 256, 0, stream>>>(
        blocks, nullptr, 768, 768, Wkvb, nullptr, bkvb, 512, stats_bkv);
    // 2. bkv = LN(bkv_raw) in-place
    ln_rows_s<false><<<8192, 256, 0, stream>>>(bkvb, stats_bkv, kvn_g, kvn_b);
    // 3. kvbb = bkv @ [wk;wv]^T + [bk;bv]                         [8192,1024]
    gemm_bf16<0, false><<<dim3(8, 64), 256, 0, stream>>>(
        bkvb, nullptr, 512, 512, inwb + 512 * 512, in_b + 512, kvbb, 1024, nullptr);
    // 4. q_raw = lines @ Wq^T  (fp32 A direct, bf16 + stats)      [32768,512]
    gemm_bf16<1, true><<<dim3(4, 256), 256, 0, stream>>>(
        lines, nullptr, 768, 768, Wqb, nullptr, qb, 512, stats_q);
    // 5. q = LN(q_raw) in-place
    ln_rows_s<false><<<32768, 256, 0, stream>>>(qb, stats_q, qn_g, qn_b);
    // 6. qh = q @ wq_i^T + bq_i                                   [32768,512]
    gemm_bf16<0, false><<<dim3(4, 256), 256, 0, stream>>>(
        qb, nullptr, 512, 512, inwb, in_b, qhb, 512, nullptr);
    // 7. ctx (attention, persistent grid)
    attn_kernel<<<2048, 512, 0, stream>>>(qhb, kvbb, kidx, ncnt, ctxb);
    // 8. h1_raw = q@p1a^T + ctx@W2^T + bias2  (into qhb; qh dead) + stats
    gemm_bf16<2, true><<<dim3(4, 256), 256, 0, stream>>>(
        qb, ctxb, 512, 1024, p1cb, bias2f, qhb, 512, stats_h1);
    // 9. h1 = gelu(LN(h1_raw)) in-place
    ln_rows_s<true><<<32768, 256, 0, stream>>>(qhb, stats_h1, ln1_g, ln1_b);
    // 10. h2_raw = h1 @ p2_w^T + p2_b  (into ctxb; ctx dead) + stats
    gemm_bf16<0, true><<<dim3(4, 256), 256, 0, stream>>>(
        qhb, nullptr, 512, 512, p2wb, p2_b, ctxb, 512, stats_h2);
    // 11. out = sigmoid((h1 + gelu(LN(h2_raw))) . head_w + head_b)
    final_head_s<<<32768, 256, 0, stream>>>(qhb, ctxb, stats_h2, ln2_g, ln2_b,
                                            head_w, head_b, out);
}